// Round 14
// baseline (5471.525 us; speedup 1.0000x reference)
//
#include <hip/hip_runtime.h>
#include <math.h>

#define kB 8
#define kN 4096
#define kBN (kB * kN)
#define kK 30
#define kCH 8192   // head row-chunk
#define kDQ 2048   // knn D-chunk query rows

typedef __attribute__((ext_vector_type(8))) short short8v;
typedef __attribute__((ext_vector_type(4))) float f32x4v;

__device__ __forceinline__ unsigned short bf16hi(float a) {
  union { float f; unsigned u; } v; v.f = a;
  unsigned r = v.u + 0x7FFF + ((v.u >> 16) & 1);
  return (unsigned short)(r >> 16);
}
__device__ __forceinline__ float bf16tof(unsigned short h) {
  union { float f; unsigned u; } v; v.u = ((unsigned)h) << 16;
  return v.f;
}

// ----------------------------- concat x0 (padded to 8 ch) -----------------
__global__ void concat_x0_kernel(const float* __restrict__ x,
                                 const float* __restrict__ pos,
                                 float* __restrict__ x0p) {
  int e = blockIdx.x * 256 + threadIdx.x;
  if (e >= kBN * 8) return;
  int p = e / 8, c = e % 8;
  float v = 0.f;
  if (c < 3) v = x[(size_t)p * 3 + c];
  else if (c < 6) v = pos[(size_t)p * 3 + (c - 3)];
  x0p[e] = v;
}

// ------------------------------ norms ------------------------------------
template <int C, int CS>
__global__ void norms_kernel(const float* __restrict__ X, float* __restrict__ nrm) {
  int p = blockIdx.x * 256 + threadIdx.x;
  if (p >= kBN) return;
  const float* xp = X + (size_t)p * CS;
  float s = 0.f;
  for (int c = 0; c < C; ++c) s = fmaf(xp[c], xp[c], s);
  nrm[p] = s;
}

// --------------------------- kNN: distance GEMM ----------------------------
// 128x128 tile, 8x8 acc/thread (64 fma per 4 ds_read_b128 -> VALU-bound).
// Per-output fma chain is ascending-k scalar -> bit-identical distances.
template <int CS>
__global__ __launch_bounds__(256) void dist_gemm_kernel(
    const float* __restrict__ X, const float* __restrict__ nrm,
    float* __restrict__ D, int i0) {
  __shared__ float As[CS][128 + 4];
  __shared__ float Bs[CS][128 + 4];
  const int tid = threadIdx.x;
  const int tx = tid & 15, ty = tid >> 4;   // 8 cols x 8 rows per thread
  const int rI = i0 + blockIdx.y * 128;
  const int cJ = blockIdx.x * 128;

  constexpr int QUADS = CS / 4;
  for (int e = tid; e < 128 * QUADS; e += 256) {
    int r = e & 127, q = e >> 7;
    float4 v = *reinterpret_cast<const float4*>(X + (size_t)(rI + r) * CS + q * 4);
    As[q * 4 + 0][r] = v.x; As[q * 4 + 1][r] = v.y;
    As[q * 4 + 2][r] = v.z; As[q * 4 + 3][r] = v.w;
  }
  for (int e = tid; e < 128 * QUADS; e += 256) {
    int r = e & 127, q = e >> 7;
    float4 v = *reinterpret_cast<const float4*>(X + (size_t)(cJ + r) * CS + q * 4);
    Bs[q * 4 + 0][r] = v.x; Bs[q * 4 + 1][r] = v.y;
    Bs[q * 4 + 2][r] = v.z; Bs[q * 4 + 3][r] = v.w;
  }
  __syncthreads();

  float acc[8][8] = {};
  #pragma unroll
  for (int k = 0; k < CS; ++k) {
    float4 a4a = *reinterpret_cast<const float4*>(&As[k][ty * 8]);
    float4 a4b = *reinterpret_cast<const float4*>(&As[k][ty * 8 + 4]);
    float4 b4a = *reinterpret_cast<const float4*>(&Bs[k][tx * 8]);
    float4 b4b = *reinterpret_cast<const float4*>(&Bs[k][tx * 8 + 4]);
    float av[8] = {a4a.x, a4a.y, a4a.z, a4a.w, a4b.x, a4b.y, a4b.z, a4b.w};
    float bv[8] = {b4a.x, b4a.y, b4a.z, b4a.w, b4b.x, b4b.y, b4b.z, b4b.w};
    #pragma unroll
    for (int i2 = 0; i2 < 8; ++i2)
      #pragma unroll
      for (int j2 = 0; j2 < 8; ++j2)
        acc[i2][j2] = fmaf(av[i2], bv[j2], acc[i2][j2]);
  }

  float ni[8], nj[8];
  #pragma unroll
  for (int i2 = 0; i2 < 8; ++i2) ni[i2] = nrm[rI + ty * 8 + i2];
  #pragma unroll
  for (int j2 = 0; j2 < 8; ++j2) nj[j2] = nrm[cJ + tx * 8 + j2];

  #pragma unroll
  for (int i2 = 0; i2 < 8; ++i2) {
    float4 oa, ob;
    oa.x = fmaf(2.f, acc[i2][0], -ni[i2]) - nj[0];
    oa.y = fmaf(2.f, acc[i2][1], -ni[i2]) - nj[1];
    oa.z = fmaf(2.f, acc[i2][2], -ni[i2]) - nj[2];
    oa.w = fmaf(2.f, acc[i2][3], -ni[i2]) - nj[3];
    ob.x = fmaf(2.f, acc[i2][4], -ni[i2]) - nj[4];
    ob.y = fmaf(2.f, acc[i2][5], -ni[i2]) - nj[5];
    ob.z = fmaf(2.f, acc[i2][6], -ni[i2]) - nj[6];
    ob.w = fmaf(2.f, acc[i2][7], -ni[i2]) - nj[7];
    float* dp = &D[(size_t)(blockIdx.y * 128 + ty * 8 + i2) * kN + cJ + tx * 8];
    *reinterpret_cast<float4*>(dp) = oa;
    *reinterpret_cast<float4*>(dp + 4) = ob;
  }
}

// --------------------------- kNN: selection --------------------------------
__global__ __launch_bounds__(256) void knn_select_kernel(
    const float* __restrict__ D, int* __restrict__ idx_out, int qbase) {
  const int w = threadIdx.x >> 6;
  const int l = threadIdx.x & 63;
  const int q = blockIdx.x * 4 + w;
  const float* __restrict__ row = D + (size_t)q * kN;

  float d[64];
  #pragma unroll
  for (int m = 0; m < 64; ++m) d[m] = row[m * 64 + l];

  float gv[4];
  int gm[4];
  #pragma unroll
  for (int g = 0; g < 4; ++g) {
    float bv = -INFINITY;
    int bm = g * 16;
    #pragma unroll
    for (int mm = 0; mm < 16; ++mm) {
      const int m = g * 16 + mm;
      if (d[m] > bv) { bv = d[m]; bm = m; }
    }
    gv[g] = bv;
    gm[g] = bm;
  }

  int myout = 0;
  for (int k = 0; k < kK; ++k) {
    float cv = gv[0];
    int cm = gm[0];
    if (gv[1] > cv) { cv = gv[1]; cm = gm[1]; }
    if (gv[2] > cv) { cv = gv[2]; cm = gm[2]; }
    if (gv[3] > cv) { cv = gv[3]; cm = gm[3]; }
    int cj = cm * 64 + l;
    #pragma unroll
    for (int off = 32; off > 0; off >>= 1) {
      float ov = __shfl_xor(cv, off);
      int oj = __shfl_xor(cj, off);
      if (ov > cv || (ov == cv && oj < cj)) { cv = ov; cj = oj; }
    }
    if (l == k) myout = cj;
    if ((cj & 63) == l) {
      const int om = cj >> 6;
      const int g = om >> 4;
#define RESCAN_GROUP(G)                                                  \
  {                                                                      \
    float nv = -INFINITY;                                                \
    int nm = (G) * 16;                                                   \
    _Pragma("unroll") for (int mm = 0; mm < 16; ++mm) {                  \
      const int m = (G) * 16 + mm;                                       \
      float dd = (m == om) ? -INFINITY : d[m];                           \
      d[m] = dd;                                                         \
      if (dd > nv) { nv = dd; nm = m; }                                  \
    }                                                                    \
    gv[G] = nv;                                                          \
    gm[G] = nm;                                                          \
  }
      if (g == 0) RESCAN_GROUP(0)
      else if (g == 1) RESCAN_GROUP(1)
      else if (g == 2) RESCAN_GROUP(2)
      else RESCAN_GROUP(3)
#undef RESCAN_GROUP
    }
  }
  if (l < kK) idx_out[(size_t)(qbase + q) * kK + l] = myout;
}

// -------------------- EdgeConv via U/V decomposition -----------------------
__global__ void prep_uv_kernel(const float* __restrict__ W1,
                               const float* __restrict__ b1,
                               float* __restrict__ wu, float* __restrict__ b1e,
                               int C, int H1, int CS) {
  const int n2 = 2 * H1;
  int e = blockIdx.x * 256 + threadIdx.x;
  if (e < n2) b1e[e] = (e < H1) ? b1[e] : 0.f;
  if (e >= CS * n2) return;
  int c = e / n2, n = e % n2;
  float v;
  if (c >= C) v = 0.f;
  else if (n < H1) v = W1[(size_t)c * H1 + n] - W1[(size_t)(C + c) * H1 + n];
  else v = W1[(size_t)(C + c) * H1 + (n - H1)];
  wu[e] = v;
}

// gather + GEMM2 + max (fp32): 4 points x 32 padded edges (128 rows) x 64
// cols per block, 8x4 fragments. fma order per output unchanged (bit-exact).
// Used for e1-e3 (outputs feed kNN).
template <int H1>
__global__ __launch_bounds__(256) void gather_gemm2_max_kernel(
    const float* __restrict__ UV, const int* __restrict__ nidx,
    const float* __restrict__ W2, const float* __restrict__ b2,
    float* __restrict__ Y, int H2) {
  __shared__ float As[32][128 + 4];
  __shared__ float Ws[32][64];
  __shared__ float red[16][64 + 4];

  const int tid = threadIdx.x;
  const int tx = tid & 15, ty = tid >> 4;   // 4 cols x 8 rows per thread
  const int p0 = blockIdx.y * 4;
  const int n0 = blockIdx.x * 64;
  const int N2 = 2 * H1;

  // A-build: row r = tid>>1 (128 rows), half = tid&1 owns quads {0..3}+4*half
  const int r = tid >> 1;
  const int half = tid & 1;
  const int pt = p0 + (r >> 5);
  int e = r & 31;
  if (e >= kK) e = 0;  // pad rows duplicate edge 0 -> max unchanged
  const int j = nidx[(size_t)pt * kK + e];
  const int jglob = (pt & ~(kN - 1)) + j;
  const float* __restrict__ Urow = UV + (size_t)pt * N2;
  const float* __restrict__ Vrow = UV + (size_t)jglob * N2 + H1;

  const int wk = tid >> 6;
  const int wn = tid & 63;

  float acc[8][4] = {};

  #pragma unroll
  for (int k0 = 0; k0 < H1; k0 += 32) {
    #pragma unroll
    for (int kq = 0; kq < 4; ++kq) {
      const int kk4 = half * 16 + kq * 4;
      float4 u4 = *reinterpret_cast<const float4*>(Urow + k0 + kk4);
      float4 v4 = *reinterpret_cast<const float4*>(Vrow + k0 + kk4);
      As[kk4 + 0][r] = fmaxf(u4.x + v4.x, 0.f);
      As[kk4 + 1][r] = fmaxf(u4.y + v4.y, 0.f);
      As[kk4 + 2][r] = fmaxf(u4.z + v4.z, 0.f);
      As[kk4 + 3][r] = fmaxf(u4.w + v4.w, 0.f);
    }
    #pragma unroll
    for (int qq = 0; qq < 8; ++qq)
      Ws[wk + qq * 4][wn] = W2[(size_t)(k0 + wk + qq * 4) * H2 + n0 + wn];
    __syncthreads();
    #pragma unroll
    for (int kk = 0; kk < 32; ++kk) {
      float4 a4a = *reinterpret_cast<const float4*>(&As[kk][ty * 8]);
      float4 a4b = *reinterpret_cast<const float4*>(&As[kk][ty * 8 + 4]);
      float4 b4 = *reinterpret_cast<const float4*>(&Ws[kk][tx * 4]);
      float av[8] = {a4a.x, a4a.y, a4a.z, a4a.w, a4b.x, a4b.y, a4b.z, a4b.w};
      float bv[4] = {b4.x, b4.y, b4.z, b4.w};
      #pragma unroll
      for (int i2 = 0; i2 < 8; ++i2)
        #pragma unroll
        for (int j2 = 0; j2 < 4; ++j2)
          acc[i2][j2] = fmaf(av[i2], bv[j2], acc[i2][j2]);
    }
    __syncthreads();
  }

  // per-thread 8-row max (rows ty*8.. all within point ty>>2)
  #pragma unroll
  for (int j2 = 0; j2 < 4; ++j2) {
    float m = acc[0][j2];
    #pragma unroll
    for (int i2 = 1; i2 < 8; ++i2) m = fmaxf(m, acc[i2][j2]);
    red[ty][tx * 4 + j2] = m;
  }
  __syncthreads();
  {
    int ptl = tid >> 6, c = tid & 63;   // 4 points x 64 cols = 256 threads
    float m = red[ptl * 4][c];
    #pragma unroll
    for (int qq = 1; qq < 4; ++qq) m = fmaxf(m, red[ptl * 4 + qq][c]);
    Y[(size_t)(p0 + ptl) * H2 + n0 + c] = m + b2[n0 + c];
  }
}

// ---------------- pack feW2 (1024x1024) into MFMA fragment order -----------
__global__ void pack_w2_kernel(const float* __restrict__ W2,
                               unsigned short* __restrict__ wp) {
  int e = blockIdx.x * 256 + threadIdx.x;
  if (e >= 64 * 32 * 64 * 8) return;
  int i = e & 7;
  int lane = (e >> 3) & 63;
  int ks = (e >> 9) & 31;
  int tg = e >> 14;
  int n = tg * 16 + (lane & 15);
  int k = ks * 32 + (lane >> 4) * 8 + i;
  float w = W2[(size_t)k * 1024 + n];
  unsigned short hi = bf16hi(w);
  unsigned short lo = bf16hi(w - bf16tof(hi));
  size_t base = ((size_t)(tg * 32 + ks) * 64 + lane) * 16;
  wp[base + i] = hi;
  wp[base + 8 + i] = lo;
}

// ---------------- generic pack (K x N) into MFMA fragment order ------------
__global__ void pack_w2gen_kernel(const float* __restrict__ W2,
                                  unsigned short* __restrict__ wp,
                                  int H1, int H2) {
  int e = blockIdx.x * 256 + threadIdx.x;
  int nks = H1 / 32;
  int total = (H2 / 16) * nks * 64 * 8;
  if (e >= total) return;
  int i = e & 7;
  int lane = (e >> 3) & 63;
  int rem = e >> 9;
  int ks = rem % nks;
  int tg = rem / nks;
  int n = tg * 16 + (lane & 15);
  int k = ks * 32 + (lane >> 4) * 8 + i;
  float w = W2[(size_t)k * H2 + n];
  unsigned short hi = bf16hi(w);
  unsigned short lo = bf16hi(w - bf16tof(hi));
  size_t base = ((size_t)(tg * nks + ks) * 64 + lane) * 16;
  wp[base + i] = hi;
  wp[base + 8 + i] = lo;
}

// -------- e4 gather + split-bf16 MFMA + max (H1=128, H2=128) ---------------
#define SPL8(h, l, i, val)                                        \
  { float _v = (val); unsigned short _h = bf16hi(_v);             \
    h[i] = (short)_h; l[i] = (short)bf16hi(_v - bf16tof(_h)); }

__global__ __launch_bounds__(256) void gather_mfma_max_kernel(
    const float* __restrict__ UV, const int* __restrict__ nidx,
    const unsigned short* __restrict__ wpk, const float* __restrict__ b2,
    float* __restrict__ Y) {
  const int t = threadIdx.x;
  const int l = t & 63;
  const int wv = t >> 6;
  const int pt = blockIdx.x * 4 + wv;
  const int arow = l & 15;
  const int kgrp = l >> 4;

  const int base = pt & ~(kN - 1);
  int e1 = 16 + arow;
  if (e1 >= kK) e1 = 0;
  const int j0 = base + nidx[(size_t)pt * kK + arow];
  const int j1 = base + nidx[(size_t)pt * kK + e1];
  const float* __restrict__ U  = UV + (size_t)pt * 256;
  const float* __restrict__ V0 = UV + (size_t)j0 * 256 + 128;
  const float* __restrict__ V1 = UV + (size_t)j1 * 256 + 128;

  f32x4v acc0[8], acc1[8];
  f32x4v zz = {0.f, 0.f, 0.f, 0.f};
  #pragma unroll
  for (int i = 0; i < 8; ++i) { acc0[i] = zz; acc1[i] = zz; }

  #pragma unroll
  for (int ks = 0; ks < 4; ++ks) {
    const int kb = ks * 32 + kgrp * 8;
    float4 ua = *reinterpret_cast<const float4*>(U + kb);
    float4 ub = *reinterpret_cast<const float4*>(U + kb + 4);
    float4 va = *reinterpret_cast<const float4*>(V0 + kb);
    float4 vb = *reinterpret_cast<const float4*>(V0 + kb + 4);
    short8v a0h, a0l;
    SPL8(a0h, a0l, 0, fmaxf(ua.x + va.x, 0.f));
    SPL8(a0h, a0l, 1, fmaxf(ua.y + va.y, 0.f));
    SPL8(a0h, a0l, 2, fmaxf(ua.z + va.z, 0.f));
    SPL8(a0h, a0l, 3, fmaxf(ua.w + va.w, 0.f));
    SPL8(a0h, a0l, 4, fmaxf(ub.x + vb.x, 0.f));
    SPL8(a0h, a0l, 5, fmaxf(ub.y + vb.y, 0.f));
    SPL8(a0h, a0l, 6, fmaxf(ub.z + vb.z, 0.f));
    SPL8(a0h, a0l, 7, fmaxf(ub.w + vb.w, 0.f));
    va = *reinterpret_cast<const float4*>(V1 + kb);
    vb = *reinterpret_cast<const float4*>(V1 + kb + 4);
    short8v a1h, a1l;
    SPL8(a1h, a1l, 0, fmaxf(ua.x + va.x, 0.f));
    SPL8(a1h, a1l, 1, fmaxf(ua.y + va.y, 0.f));
    SPL8(a1h, a1l, 2, fmaxf(ua.z + va.z, 0.f));
    SPL8(a1h, a1l, 3, fmaxf(ua.w + va.w, 0.f));
    SPL8(a1h, a1l, 4, fmaxf(ub.x + vb.x, 0.f));
    SPL8(a1h, a1l, 5, fmaxf(ub.y + vb.y, 0.f));
    SPL8(a1h, a1l, 6, fmaxf(ub.z + vb.z, 0.f));
    SPL8(a1h, a1l, 7, fmaxf(ub.w + vb.w, 0.f));
    #pragma unroll
    for (int tg = 0; tg < 8; ++tg) {
      const unsigned short* bp = wpk + ((size_t)(tg * 4 + ks) * 64 + l) * 16;
      short8v bh = *reinterpret_cast<const short8v*>(bp);
      short8v bl = *reinterpret_cast<const short8v*>(bp + 8);
      acc0[tg] = __builtin_amdgcn_mfma_f32_16x16x32_bf16(a0h, bh, acc0[tg], 0, 0, 0);
      acc0[tg] = __builtin_amdgcn_mfma_f32_16x16x32_bf16(a0h, bl, acc0[tg], 0, 0, 0);
      acc0[tg] = __builtin_amdgcn_mfma_f32_16x16x32_bf16(a0l, bh, acc0[tg], 0, 0, 0);
      acc1[tg] = __builtin_amdgcn_mfma_f32_16x16x32_bf16(a1h, bh, acc1[tg], 0, 0, 0);
      acc1[tg] = __builtin_amdgcn_mfma_f32_16x16x32_bf16(a1h, bl, acc1[tg], 0, 0, 0);
      acc1[tg] = __builtin_amdgcn_mfma_f32_16x16x32_bf16(a1l, bh, acc1[tg], 0, 0, 0);
    }
  }

  #pragma unroll
  for (int tg = 0; tg < 8; ++tg) {
    float m = fmaxf(fmaxf(acc0[tg][0], acc0[tg][1]),
                    fmaxf(acc0[tg][2], acc0[tg][3]));
    m = fmaxf(m, fmaxf(fmaxf(acc1[tg][0], acc1[tg][1]),
                       fmaxf(acc1[tg][2], acc1[tg][3])));
    m = fmaxf(m, __shfl_xor(m, 16));
    m = fmaxf(m, __shfl_xor(m, 32));
    if (kgrp == 0) {
      int n = tg * 16 + arow;
      Y[(size_t)pt * 128 + n] = m + b2[n];
    }
  }
}

// ------- fused fe: both phases MFMA; col-half split, XCD-keyed mapping ------
// Block = (row-tile rt, col-half ch) with ch = (blockIdx.x%8)>>2 so each
// XCD's L2 holds one 2.3MB wpack half. Phase 1 (full h1) duplicated per
// half (identical values). Per-output math unchanged.
#define FRT 16
__global__ __launch_bounds__(256) void fe_fused_kernel(
    const float* __restrict__ x4, const unsigned short* __restrict__ wpf1,
    const float* __restrict__ b1, const unsigned short* __restrict__ wpack,
    const float* __restrict__ b2, float* __restrict__ part) {
  __shared__ unsigned short xh[FRT][136];
  __shared__ unsigned short xl[FRT][136];
  __shared__ unsigned short h1h[FRT][1032];
  __shared__ unsigned short h1l[FRT][1032];
  const int bi = blockIdx.x;
  const int ch = (bi >> 2) & 1;
  const int tile = ((bi >> 3) << 2) | (bi & 3);
  const int r0 = tile * FRT;
  const int t = threadIdx.x;

  for (int e = t; e < FRT * 32; e += 256) {
    int r = e / 32, c4 = e % 32;
    float4 v = *reinterpret_cast<const float4*>(&x4[(size_t)(r0 + r) * 128 + c4 * 4]);
    unsigned short h0 = bf16hi(v.x), h1_ = bf16hi(v.y), h2 = bf16hi(v.z), h3 = bf16hi(v.w);
    xh[r][c4 * 4 + 0] = h0; xh[r][c4 * 4 + 1] = h1_;
    xh[r][c4 * 4 + 2] = h2; xh[r][c4 * 4 + 3] = h3;
    xl[r][c4 * 4 + 0] = bf16hi(v.x - bf16tof(h0));
    xl[r][c4 * 4 + 1] = bf16hi(v.y - bf16tof(h1_));
    xl[r][c4 * 4 + 2] = bf16hi(v.z - bf16tof(h2));
    xl[r][c4 * 4 + 3] = bf16hi(v.w - bf16tof(h3));
  }
  __syncthreads();

  const int l = t & 63;
  const int wv = t >> 6;
  const int arow = l & 15;
  const int kgrp = l >> 4;

  // ---- phase 1: h1 = relu(x4@W1 + b1), full 1024 cols ----
  {
    short8v ahv[4], alv[4];
    #pragma unroll
    for (int ks = 0; ks < 4; ++ks) {
      ahv[ks] = *reinterpret_cast<const short8v*>(&xh[arow][ks * 32 + kgrp * 8]);
      alv[ks] = *reinterpret_cast<const short8v*>(&xl[arow][ks * 32 + kgrp * 8]);
    }
    #pragma unroll
    for (int tg = 0; tg < 16; ++tg) {
      const int tgg = wv * 16 + tg;
      f32x4v a1 = {0.f, 0.f, 0.f, 0.f};
      #pragma unroll
      for (int ks = 0; ks < 4; ++ks) {
        const unsigned short* bp = wpf1 + ((size_t)(tgg * 4 + ks) * 64 + l) * 16;
        short8v bh = *reinterpret_cast<const short8v*>(bp);
        short8v bl = *reinterpret_cast<const short8v*>(bp + 8);
        a1 = __builtin_amdgcn_mfma_f32_16x16x32_bf16(ahv[ks], bh, a1, 0, 0, 0);
        a1 = __builtin_amdgcn_mfma_f32_16x16x32_bf16(ahv[ks], bl, a1, 0, 0, 0);
        a1 = __builtin_amdgcn_mfma_f32_16x16x32_bf16(alv[ks], bh, a1, 0, 0, 0);
      }
      const int col = tgg * 16 + arow;
      const float bb = b1[col];
      #pragma unroll
      for (int i = 0; i < 4; ++i) {
        float v = fmaxf(a1[i] + bb, 0.f);
        unsigned short h = bf16hi(v);
        h1h[kgrp * 4 + i][col] = h;
        h1l[kgrp * 4 + i][col] = bf16hi(v - bf16tof(h));
      }
    }
  }
  __syncthreads();

  // ---- phase 2: this block's col-half (512 cols), tg-chunked, B dbuf ----
  #pragma unroll
  for (int tc = 0; tc < 2; ++tc) {
    f32x4v accm[4];
    f32x4v zz = {0.f, 0.f, 0.f, 0.f};
    #pragma unroll
    for (int i = 0; i < 4; ++i) accm[i] = zz;

    const int tgb = ch * 32 + wv * 8 + tc * 4;
    short8v bhC[4], blC[4], bhN[4], blN[4];
    #pragma unroll
    for (int tt = 0; tt < 4; ++tt) {
      const unsigned short* bp = wpack + ((size_t)((tgb + tt) * 32 + 0) * 64 + l) * 16;
      bhC[tt] = *reinterpret_cast<const short8v*>(bp);
      blC[tt] = *reinterpret_cast<const short8v*>(bp + 8);
    }
    for (int ks = 0; ks < 32; ++ks) {
      if (ks < 31) {
        #pragma unroll
        for (int tt = 0; tt < 4; ++tt) {
          const unsigned short* bp =
              wpack + ((size_t)((tgb + tt) * 32 + ks + 1) * 64 + l) * 16;
          bhN[tt] = *reinterpret_cast<const short8v*>(bp);
          blN[tt] = *reinterpret_cast<const short8v*>(bp + 8);
        }
      }
      const int kb = ks * 32 + kgrp * 8;
      short8v ah = *reinterpret_cast<const short8v*>(&h1h[arow][kb]);
      short8v al = *reinterpret_cast<const short8v*>(&h1l[arow][kb]);
      #pragma unroll
      for (int tt = 0; tt < 4; ++tt) {
        accm[tt] = __builtin_amdgcn_mfma_f32_16x16x32_bf16(ah, bhC[tt], accm[tt], 0, 0, 0);
        accm[tt] = __builtin_amdgcn_mfma_f32_16x16x32_bf16(ah, blC[tt], accm[tt], 0, 0, 0);
        accm[tt] = __builtin_amdgcn_mfma_f32_16x16x32_bf16(al, bhC[tt], accm[tt], 0, 0, 0);
      }
      #pragma unroll
      for (int tt = 0; tt < 4; ++tt) { bhC[tt] = bhN[tt]; blC[tt] = blN[tt]; }
    }
    #pragma unroll
    for (int tt = 0; tt < 4; ++tt) {
      float m = fmaxf(fmaxf(accm[tt][0], accm[tt][1]),
                      fmaxf(accm[tt][2], accm[tt][3]));
      m = fmaxf(m, __shfl_xor(m, 16));
      m = fmaxf(m, __shfl_xor(m, 32));
      if (kgrp == 0) {
        int n = (tgb + tt) * 16 + arow;
        part[(size_t)tile * 1024 + n] = m + b2[n];
      }
    }
  }
}

// --------------------------- reduce partials -> g ---------------------------
__global__ void reduce_g_kernel(const float* __restrict__ part, float* __restrict__ g) {
  int e = blockIdx.x * 256 + threadIdx.x;
  if (e >= kB * 1024) return;
  int b = e / 1024, c = e % 1024;
  const int tilesPerBatch = kN / FRT;  // 256
  const float* p = part + (size_t)b * tilesPerBatch * 1024 + c;
  float m = -INFINITY;
  for (int t = 0; t < tilesPerBatch; ++t) m = fmaxf(m, p[(size_t)t * 1024]);
  g[e] = m;
}

// --------------- per-batch head-0 g-contribution: gvec = g@W[326:]+b -------
__global__ void ghead_kernel(const float* __restrict__ g,
                             const float* __restrict__ h0W,
                             const float* __restrict__ h0b,
                             float* __restrict__ gvec) {
  const int b = blockIdx.x;
  const int n = threadIdx.x;
  float acc = h0b[n];
  const float* gb = g + (size_t)b * 1024;
  for (int k = 0; k < 1024; ++k)
    acc = fmaf(gb[k], h0W[(size_t)(326 + k) * 256 + n], acc);
  gvec[b * 256 + n] = acc;
}

// ---------- head MFMA GEMM: out = act(A@B + bias), A fp32 chunk-local ------
template <int KD, int NN>
__global__ __launch_bounds__(256) void head_mfma_kernel(
    const float* __restrict__ A, const unsigned short* __restrict__ bpk,
    const float* __restrict__ bias, float* __restrict__ out, int relu) {
  constexpr int NKS = KD / 32;
  __shared__ unsigned short ah[32][KD + 8];
  __shared__ unsigned short al[32][KD + 8];
  const int t = threadIdx.x;
  const int m0 = blockIdx.y * 32;
  const int n0 = blockIdx.x * 128;

  for (int e = t; e < 32 * (KD / 4); e += 256) {
    int r = e / (KD / 4), c4 = e % (KD / 4);
    float4 v = *reinterpret_cast<const float4*>(&A[(size_t)(m0 + r) * KD + c4 * 4]);
    unsigned short h0 = bf16hi(v.x), h1 = bf16hi(v.y), h2 = bf16hi(v.z), h3 = bf16hi(v.w);
    ah[r][c4 * 4 + 0] = h0; ah[r][c4 * 4 + 1] = h1;
    ah[r][c4 * 4 + 2] = h2; ah[r][c4 * 4 + 3] = h3;
    al[r][c4 * 4 + 0] = bf16hi(v.x - bf16tof(h0));
    al[r][c4 * 4 + 1] = bf16hi(v.y - bf16tof(h1));
    al[r][c4 * 4 + 2] = bf16hi(v.z - bf16tof(h2));
    al[r][c4 * 4 + 3] = bf16hi(v.w - bf16tof(h3));
  }
  __syncthreads();

  const int l = t & 63;
  const int wv = t >> 6;
  const int rf = wv >> 1;
  const int ch = wv & 1;
  const int arow = rf * 16 + (l & 15);
  const int kgrp = l >> 4;

  f32x4v acc[4];
  f32x4v zz = {0.f, 0.f, 0.f, 0.f};
  #pragma unroll
  for (int i = 0; i < 4; ++i) acc[i] = zz;

  for (int ks = 0; ks < NKS; ++ks) {
    const int kb = ks * 32 + kgrp * 8;
    short8v a_h = *reinterpret_cast<const short8v*>(&ah[arow][kb]);
    short8v a_l = *reinterpret_cast<const short8v*>(&al[arow][kb]);
    #pragma unroll
    for (int tg = 0; tg < 4; ++tg) {
      const int tgg = n0 / 16 + ch * 4 + tg;
      const unsigned short* bp = bpk + ((size_t)(tgg * NKS + ks) * 64 + l) * 16;
      short8v bh = *reinterpret_cast<const short8v*>(bp);
      short8v bl = *reinterpret_cast<const short8v*>(bp + 8);
      acc[tg] = __builtin_amdgcn_mfma_f32_16x16x32_bf16(a_h, bh, acc[tg], 0, 0, 0);
      acc[tg] = __builtin_amdgcn_mfma_f32_16x16x32_bf16(a_h, bl, acc[tg], 0, 0, 0);
      acc[tg] = __builtin_amdgcn_mfma_f32_16x16x32_bf16(a_l, bh, acc[tg], 0, 0, 0);
    }
  }

  #pragma unroll
  for (int tg = 0; tg < 4; ++tg) {
    int col = n0 + (ch * 4 + tg) * 16 + (l & 15);
    float bb = bias[col];
    #pragma unroll
    for (int i = 0; i < 4; ++i) {
      int row = m0 + rf * 16 + kgrp * 4 + i;
      float v = acc[tg][i] + bb;
      if (relu) v = fmaxf(v, 0.f);
      out[(size_t)row * NN + col] = v;
    }
  }
}

// ------------------------------- GEMM --------------------------------------
struct FeatSrc {
  const float* x0; const float* x1; const float* x2;
  const float* x3; const float* x4; const float* g;
};

template <int ASRC>
__device__ __forceinline__ float a_fetch(const float* __restrict__ A,
                                         const FeatSrc& fs, int row, int k, int Kd) {
  if constexpr (ASRC == 0) {
    return A[(size_t)row * Kd + k];
  } else {
    if (k < 6)        return fs.x0[(size_t)row * 8 + k];
    else if (k < 70)  return fs.x1[(size_t)row * 64 + (k - 6)];
    else if (k < 134) return fs.x2[(size_t)row * 64 + (k - 70)];
    else if (k < 198) return fs.x3[(size_t)row * 64 + (k - 134)];
    else              return fs.x4[(size_t)row * 128 + (k - 198)];
  }
}

#define GBM 64
#define GBN 64
#define GBK 16

template <int ASRC>
__global__ __launch_bounds__(256) void gemm_kernel(
    const float* __restrict__ A, FeatSrc fs,
    const float* __restrict__ Bm, const float* __restrict__ bias,
    float* __restrict__ out, int row0, int Nn, int Kd, int relu, int biasb) {
  __shared__ float As[GBK][GBM + 4];
  __shared__ float Bs[GBK][GBN];

  const int tid = threadIdx.x;
  const int tx = tid % 16, ty = tid / 16;
  const int m0 = blockIdx.y * GBM;
  const int n0 = blockIdx.x * GBN;

  float acc[4][4] = {};

  for (int k0 = 0; k0 < Kd; k0 += GBK) {
    #pragma unroll
    for (int r = 0; r < 4; ++r) {
      int ee = tid + r * 256;
      int ar = ee / GBK, ak = ee % GBK;
      int kk = k0 + ak;
      float v = 0.f;
      if (kk < Kd) {
        int arow = (ASRC == 1) ? (row0 + m0 + ar) : (m0 + ar);
        v = a_fetch<ASRC>(A, fs, arow, kk, Kd);
      }
      As[ak][ar] = v;
    }
    #pragma unroll
    for (int r = 0; r < 4; ++r) {
      int ee = tid + r * 256;
      int bk = ee / GBN, bn = ee % GBN;
      int kk = k0 + bk;
      float v = 0.f;
      if (kk < Kd && (n0 + bn) < Nn) v = Bm[(size_t)kk * Nn + n0 + bn];
      Bs[bk][bn] = v;
    }
    __syncthreads();
    #pragma unroll
    for (int kk = 0; kk < GBK; ++kk) {
      float4 a4 = *reinterpret_cast<const float4*>(&As[kk][ty * 4]);
      float4 b4 = *reinterpret_cast<const float4*>(&Bs[kk][tx * 4]);
      float av[4] = {a4.x, a4.y, a4.z, a4.w};
      float bv[4] = {b4.x, b4.y, b4.z, b4.w};
      #pragma unroll
      for (int i2 = 0; i2 < 4; ++i2)
        #pragma unroll
        for (int j2 = 0; j2 < 4; ++j2)
          acc[i2][j2] = fmaf(av[i2], bv[j2], acc[i2][j2]);
    }
    __syncthreads();
  }

  #pragma unroll
  for (int j2 = 0; j2 < 4; ++j2) {
    int n = n0 + tx * 4 + j2;
    if (n >= Nn) continue;
    #pragma unroll
    for (int i2 = 0; i2 < 4; ++i2) {
      float bb;
      if (biasb) {
        int grow = row0 + m0 + ty * 4 + i2;
        bb = bias[(size_t)(grow >> 12) * 256 + n];
      } else {
        bb = bias ? bias[n] : 0.f;
      }
      float v = acc[i2][j2] + bb;
      if (relu) v = fmaxf(v, 0.f);
      out[(size_t)(m0 + ty * 4 + i2) * Nn + n] = v;
    }
  }
}

// ------------------------------ log_softmax --------------------------------
__global__ void log_softmax_kernel(const float* __restrict__ logits,
                                   float* __restrict__ out, int row0) {
  int r = blockIdx.x * 256 + threadIdx.x;
  if (r >= kCH) return;
  const float* lp = logits + (size_t)r * 13;
  float v[13];
  float m = -INFINITY;
  #pragma unroll
  for (int c = 0; c < 13; ++c) { v[c] = lp[c]; m = fmaxf(m, v[c]); }
  float s = 0.f;
  #pragma unroll
  for (int c = 0; c < 13; ++c) s += expf(v[c] - m);
  float ls = logf(s);
  float* op = out + (size_t)(row0 + r) * 13;
  #pragma unroll
  for (int c = 0; c < 13; ++c) op[c] = v[c] - m - ls;
}

// ------------------------------- launch ------------------------------------
static void run_knn(const float* X, const float* nrm, float* Dbuf, int* nidx,
                    int CS, hipStream_t stream) {
  for (int b = 0; b < kB; ++b) {
    for (int h = 0; h < kN / kDQ; ++h) {
      if (CS == 8)
        dist_gemm_kernel<8><<<dim3(kN / 128, kDQ / 128), 256, 0, stream>>>(
            X + (size_t)b * kN * 8, nrm + (size_t)b * kN, Dbuf, h * kDQ);
      else
        dist_gemm_kernel<64><<<dim3(kN / 128, kDQ / 128), 256, 0, stream>>>(
            X + (size_t)b * kN * 64, nrm + (size_t)b * kN, Dbuf, h * kDQ);
      knn_select_kernel<<<kDQ / 4, 256, 0, stream>>>(Dbuf, nidx,
                                                     b * kN + h * kDQ);
    }
  }
}

extern "C" void kernel_launch(void* const* d_in, const int* in_sizes, int n_in,
                              void* d_out, int out_size, void* d_ws, size_t ws_size,
                              hipStream_t stream) {
  const float* x    = (const float*)d_in[0];
  const float* pos  = (const float*)d_in[1];
  const float* e1W1 = (const float*)d_in[2];
  const float* e1b1 = (const float*)d_in[3];
  const float* e1W2 = (const float*)d_in[4];
  const float* e1b2 = (const float*)d_in[5];
  const float* e2W1 = (const float*)d_in[6];
  const float* e2b1 = (const float*)d_in[7];
  const float* e2W2 = (const float*)d_in[8];
  const float* e2b2 = (const float*)d_in[9];
  const float* e3W1 = (const float*)d_in[10];
  const float* e3b1 = (const float*)d_in[11];
  const float* e3W2 = (const float*)d_in[12];
  const float* e3b2 = (const float*)d_in[13];
  const float* e4W1 = (const float*)d_in[14];
  const float* e4b1 = (const float*)d_in[15];
  const float* e4W2 = (const float*)d_in[16];
  const float* e4b2 = (const float*)d_in[17];
  const float* feW1 = (const float*)d_in[18];
  const float* feb1 = (const float*)d_in[19];
  const float* feW2 = (const float*)d_in[20];
  const float* feb2 = (const float*)d_in[21];
  const float* h0W  = (const float*)d_in[22];
  const float* h0b  = (const float*)d_in[23];
  const float* h1W  = (const float*)d_in[24];
  const float* h1b  = (const float*)d_in[25];
  const float* h2W  = (const float*)d_in[26];
  const float* h2b  = (const float*)d_in[27];
  const float* h3W  = (const float*)d_in[28];
  const float* h3b  = (const float*)d_in[29];

  float* W = (float*)d_ws;
  size_t off = 0;
  float* x0p  = W + off; off += (size_t)kBN * 8;
  float* x1   = W + off; off += (size_t)kBN * 64;
  float* x2   = W + off; off += (size_t)kBN * 64;
  float* x3   = W + off; off += (size_t)kBN * 64;
  float* x4   = W + off; off += (size_t)kBN * 128;
  float* gmax = W + off; off += (size_t)kB * 1024;
  float* gvec = W + off; off += (size_t)kB * 256;
  float* nrm  = W + off; off += (size_t)kBN;
  int*   nidx = (int*)(W + off); off += (size_t)kBN * kK;
  float* wu   = W + off; off += (size_t)64 * 256;
  float* b1e  = W + off; off += 256;
  unsigned short* wpack = (unsigned short*)(W + off); off += (size_t)1048576; // 4MB
  unsigned short* wpk4  = (unsigned short*)(W + off); off += (size_t)16384;   // 64KB
  unsigned short* wph1  = (unsigned short*)(W + off); off += (size_t)65536;   // 256KB
  unsigned short* wph2  = (unsigned short*)(W + off); off += (size_t)32768;   // 128KB
  unsigned short* wpf1  = (unsigned short*)(W + off); off += (size_t)131072;  // 512KB
  // transient union: D chunk (32MB) / uv (<=33.5MB) / fe part / head bufs
  float* trans = W + off;
  float* Dbuf = trans;
  float* uv   = trans;
  float* part = trans;
  float* ping = trans;
  float* pong = ping + (size_t)kCH * 256;
  float* h128 = pong + (size_t)kCH * 256;
  float* lgts = h128 + (size_t)kCH * 128;

  FeatSrc fs{x0p, x1, x2, x3, x4, gmax};

  concat_x0_kernel<<<(kBN * 8 + 255) / 256, 256, 0, stream>>>(x, pos, x0p);

  // ---- edge conv 1: C=6 (CS=8), H1=64, H2=64 ----
  norms_kernel<6, 8><<<(kBN + 255) / 256, 256, 0, stream>>>(x0p, nrm);
  run_knn(x0p, nrm, Dbuf, nidx, 8, stream);
  prep_uv_kernel<<<(8 * 128 + 255) / 256, 256, 0, stream>>>(e1W1, e1b1, wu, b1e, 6, 64, 8);
  gemm_kernel<0><<<dim3(128 / GBN, kBN / GBM), 256, 0, stream>>>(
      x0p, fs, wu, b1e, uv, 0, 128, 8, 0, 0);
  gather_gemm2_max_kernel<64><<<dim3(1, kBN / 4), 256, 0, stream>>>(
      uv, nidx, e1W2, e1b2, x1, 64);

  // ---- edge conv 2: C=64, H1=64, H2=64 ----
  norms_kernel<64, 64><<<(kBN + 255) / 256, 256, 0, stream>>>(x1, nrm);
  run_knn(x1, nrm, Dbuf, nidx, 64, stream);
  prep_uv_kernel<<<(64 * 128 + 255) / 256, 256, 0, stream>>>(e2W1, e2b1, wu, b1e, 64, 64, 64);
  gemm_kernel<0><<<dim3(128 / GBN, kBN / GBM), 256, 0, stream>>>(
      x1, fs, wu, b1e, uv, 0, 128, 64, 0, 0);
  gather_gemm2_max_kernel<64><<<dim3(1, kBN / 4), 256, 0, stream>>>(
      uv, nidx, e2W2, e2b2, x2, 64);

  // ---- edge conv 3 ----
  norms_kernel<64, 64><<<(kBN + 255) / 256, 256, 0, stream>>>(x2, nrm);
  run_knn(x2, nrm, Dbuf, nidx, 64, stream);
  prep_uv_kernel<<<(64 * 128 + 255) / 256, 256, 0, stream>>>(e3W1, e3b1, wu, b1e, 64, 64, 64);
  gemm_kernel<0><<<dim3(128 / GBN, kBN / GBM), 256, 0, stream>>>(
      x2, fs, wu, b1e, uv, 0, 128, 64, 0, 0);
  gather_gemm2_max_kernel<64><<<dim3(1, kBN / 4), 256, 0, stream>>>(
      uv, nidx, e3W2, e3b2, x3, 64);

  // ---- edge conv 4: C=64, H1=128, H2=128 (MFMA gather) ----
  norms_kernel<64, 64><<<(kBN + 255) / 256, 256, 0, stream>>>(x3, nrm);
  run_knn(x3, nrm, Dbuf, nidx, 64, stream);
  prep_uv_kernel<<<(64 * 256 + 255) / 256, 256, 0, stream>>>(e4W1, e4b1, wu, b1e, 64, 128, 64);
  gemm_kernel<0><<<dim3(256 / GBN, kBN / GBM), 256, 0, stream>>>(
      x3, fs, wu, b1e, uv, 0, 256, 64, 0, 0);
  pack_w2gen_kernel<<<64, 256, 0, stream>>>(e4W2, wpk4, 128, 128);
  gather_mfma_max_kernel<<<kBN / 4, 256, 0, stream>>>(uv, nidx, wpk4, e4b2, x4);

  // ---- fe fused (both phases MFMA, col-half split) + global max + ghead ----
  pack_w2_kernel<<<4096, 256, 0, stream>>>(feW2, wpack);
  pack_w2gen_kernel<<<512, 256, 0, stream>>>(feW1, wpf1, 128, 1024);
  fe_fused_kernel<<<(kBN / FRT) * 2, 256, 0, stream>>>(x4, wpf1, feb1, wpack, feb2, part);
  reduce_g_kernel<<<(kB * 1024 + 255) / 256, 256, 0, stream>>>(part, gmax);
  ghead_kernel<<<kB, 256, 0, stream>>>(gmax, h0W, h0b, gvec);

  // ---- pack head weights for MFMA (h1: 256x256, h2: 256x128) ----
  pack_w2gen_kernel<<<(16 * 8 * 512 + 255) / 256, 256, 0, stream>>>(h1W, wph1, 256, 256);
  pack_w2gen_kernel<<<(8 * 8 * 512 + 255) / 256, 256, 0, stream>>>(h2W, wph2, 256, 128);

  // ---- head, chunked over rows ----
  for (int c = 0; c < kBN / kCH; ++c) {
    int row0 = c * kCH;
    dim3 gh0(256 / GBN, kCH / GBM);
    gemm_kernel<1><<<gh0, 256, 0, stream>>>(nullptr, fs, h0W, gvec, ping, row0, 256, 326, 1, 1);
    head_mfma_kernel<256, 256><<<dim3(2, kCH / 32), 256, 0, stream>>>(
        ping, wph1, h1b, pong, 1);
    head_mfma_kernel<256, 128><<<dim3(1, kCH / 32), 256, 0, stream>>>(
        pong, wph2, h2b, h128, 1);
    dim3 gh3(1, kCH / GBM);
    gemm_kernel<0><<<gh3, 256, 0, stream>>>(h128, fs, h3W, h3b, lgts, row0, 13, 128, 0, 0);
    log_softmax_kernel<<<(kCH + 255) / 256, 256, 0, stream>>>(lgts, (float*)d_out, row0);
  }
}

// Round 15
// 5166.943 us; speedup vs baseline: 1.0589x; 1.0589x over previous
//
#include <hip/hip_runtime.h>
#include <math.h>

#define kB 8
#define kN 4096
#define kBN (kB * kN)
#define kK 30
#define kCH 8192   // head row-chunk
#define kDQ 2048   // knn D-chunk query rows

typedef __attribute__((ext_vector_type(8))) short short8v;
typedef __attribute__((ext_vector_type(4))) float f32x4v;

__device__ __forceinline__ unsigned short bf16hi(float a) {
  union { float f; unsigned u; } v; v.f = a;
  unsigned r = v.u + 0x7FFF + ((v.u >> 16) & 1);
  return (unsigned short)(r >> 16);
}
__device__ __forceinline__ float bf16tof(unsigned short h) {
  union { float f; unsigned u; } v; v.u = ((unsigned)h) << 16;
  return v.f;
}

// ----------------------------- concat x0 (padded to 8 ch) -----------------
__global__ void concat_x0_kernel(const float* __restrict__ x,
                                 const float* __restrict__ pos,
                                 float* __restrict__ x0p) {
  int e = blockIdx.x * 256 + threadIdx.x;
  if (e >= kBN * 8) return;
  int p = e / 8, c = e % 8;
  float v = 0.f;
  if (c < 3) v = x[(size_t)p * 3 + c];
  else if (c < 6) v = pos[(size_t)p * 3 + (c - 3)];
  x0p[e] = v;
}

// ------------------------------ norms ------------------------------------
template <int C, int CS>
__global__ void norms_kernel(const float* __restrict__ X, float* __restrict__ nrm) {
  int p = blockIdx.x * 256 + threadIdx.x;
  if (p >= kBN) return;
  const float* xp = X + (size_t)p * CS;
  float s = 0.f;
  for (int c = 0; c < C; ++c) s = fmaf(xp[c], xp[c], s);
  nrm[p] = s;
}

// --------------------------- kNN: distance GEMM ----------------------------
// R12-proven 64x64 tile (34.8 KB LDS -> 4 blocks/CU), lane-consecutive
// staging (bank-conflict-free). Ascending-k scalar fma per output ->
// bit-identical distances (same neighbor sets).
template <int CS>
__global__ __launch_bounds__(256) void dist_gemm_kernel(
    const float* __restrict__ X, const float* __restrict__ nrm,
    float* __restrict__ D, int i0) {
  __shared__ float As[CS][64 + 4];
  __shared__ float Bs[CS][64 + 4];
  const int tid = threadIdx.x;
  const int tx = tid & 15, ty = tid >> 4;
  const int rI = i0 + blockIdx.y * 64;
  const int cJ = blockIdx.x * 64;

  constexpr int QUADS = CS / 4;
  for (int e = tid; e < 64 * QUADS; e += 256) {
    int r = e & 63, q = e >> 6;
    float4 v = *reinterpret_cast<const float4*>(X + (size_t)(rI + r) * CS + q * 4);
    As[q * 4 + 0][r] = v.x; As[q * 4 + 1][r] = v.y;
    As[q * 4 + 2][r] = v.z; As[q * 4 + 3][r] = v.w;
  }
  for (int e = tid; e < 64 * QUADS; e += 256) {
    int r = e & 63, q = e >> 6;
    float4 v = *reinterpret_cast<const float4*>(X + (size_t)(cJ + r) * CS + q * 4);
    Bs[q * 4 + 0][r] = v.x; Bs[q * 4 + 1][r] = v.y;
    Bs[q * 4 + 2][r] = v.z; Bs[q * 4 + 3][r] = v.w;
  }
  __syncthreads();

  float acc[4][4] = {};
  #pragma unroll
  for (int k = 0; k < CS; ++k) {
    float4 a4 = *reinterpret_cast<const float4*>(&As[k][ty * 4]);
    float4 b4 = *reinterpret_cast<const float4*>(&Bs[k][tx * 4]);
    float av[4] = {a4.x, a4.y, a4.z, a4.w};
    float bv[4] = {b4.x, b4.y, b4.z, b4.w};
    #pragma unroll
    for (int i2 = 0; i2 < 4; ++i2)
      #pragma unroll
      for (int j2 = 0; j2 < 4; ++j2)
        acc[i2][j2] = fmaf(av[i2], bv[j2], acc[i2][j2]);
  }

  float ni[4], nj[4];
  #pragma unroll
  for (int i2 = 0; i2 < 4; ++i2) ni[i2] = nrm[rI + ty * 4 + i2];
  #pragma unroll
  for (int j2 = 0; j2 < 4; ++j2) nj[j2] = nrm[cJ + tx * 4 + j2];

  #pragma unroll
  for (int i2 = 0; i2 < 4; ++i2) {
    float4 o;
    o.x = fmaf(2.f, acc[i2][0], -ni[i2]) - nj[0];
    o.y = fmaf(2.f, acc[i2][1], -ni[i2]) - nj[1];
    o.z = fmaf(2.f, acc[i2][2], -ni[i2]) - nj[2];
    o.w = fmaf(2.f, acc[i2][3], -ni[i2]) - nj[3];
    *reinterpret_cast<float4*>(
        &D[(size_t)(blockIdx.y * 64 + ty * 4 + i2) * kN + cJ + tx * 4]) = o;
  }
}

// --------------------------- kNN: selection --------------------------------
__global__ __launch_bounds__(256) void knn_select_kernel(
    const float* __restrict__ D, int* __restrict__ idx_out, int qbase) {
  const int w = threadIdx.x >> 6;
  const int l = threadIdx.x & 63;
  const int q = blockIdx.x * 4 + w;
  const float* __restrict__ row = D + (size_t)q * kN;

  float d[64];
  #pragma unroll
  for (int m = 0; m < 64; ++m) d[m] = row[m * 64 + l];

  float gv[4];
  int gm[4];
  #pragma unroll
  for (int g = 0; g < 4; ++g) {
    float bv = -INFINITY;
    int bm = g * 16;
    #pragma unroll
    for (int mm = 0; mm < 16; ++mm) {
      const int m = g * 16 + mm;
      if (d[m] > bv) { bv = d[m]; bm = m; }
    }
    gv[g] = bv;
    gm[g] = bm;
  }

  int myout = 0;
  for (int k = 0; k < kK; ++k) {
    float cv = gv[0];
    int cm = gm[0];
    if (gv[1] > cv) { cv = gv[1]; cm = gm[1]; }
    if (gv[2] > cv) { cv = gv[2]; cm = gm[2]; }
    if (gv[3] > cv) { cv = gv[3]; cm = gm[3]; }
    int cj = cm * 64 + l;
    #pragma unroll
    for (int off = 32; off > 0; off >>= 1) {
      float ov = __shfl_xor(cv, off);
      int oj = __shfl_xor(cj, off);
      if (ov > cv || (ov == cv && oj < cj)) { cv = ov; cj = oj; }
    }
    if (l == k) myout = cj;
    if ((cj & 63) == l) {
      const int om = cj >> 6;
      const int g = om >> 4;
#define RESCAN_GROUP(G)                                                  \
  {                                                                      \
    float nv = -INFINITY;                                                \
    int nm = (G) * 16;                                                   \
    _Pragma("unroll") for (int mm = 0; mm < 16; ++mm) {                  \
      const int m = (G) * 16 + mm;                                       \
      float dd = (m == om) ? -INFINITY : d[m];                           \
      d[m] = dd;                                                         \
      if (dd > nv) { nv = dd; nm = m; }                                  \
    }                                                                    \
    gv[G] = nv;                                                          \
    gm[G] = nm;                                                          \
  }
      if (g == 0) RESCAN_GROUP(0)
      else if (g == 1) RESCAN_GROUP(1)
      else if (g == 2) RESCAN_GROUP(2)
      else RESCAN_GROUP(3)
#undef RESCAN_GROUP
    }
  }
  if (l < kK) idx_out[(size_t)(qbase + q) * kK + l] = myout;
}

// -------------------- EdgeConv via U/V decomposition -----------------------
__global__ void prep_uv_kernel(const float* __restrict__ W1,
                               const float* __restrict__ b1,
                               float* __restrict__ wu, float* __restrict__ b1e,
                               int C, int H1, int CS) {
  const int n2 = 2 * H1;
  int e = blockIdx.x * 256 + threadIdx.x;
  if (e < n2) b1e[e] = (e < H1) ? b1[e] : 0.f;
  if (e >= CS * n2) return;
  int c = e / n2, n = e % n2;
  float v;
  if (c >= C) v = 0.f;
  else if (n < H1) v = W1[(size_t)c * H1 + n] - W1[(size_t)(C + c) * H1 + n];
  else v = W1[(size_t)(C + c) * H1 + (n - H1)];
  wu[e] = v;
}

// gather + GEMM2 + max (fp32, 2 points x 32 edges, K-chunk 32) — e1-e3
template <int H1>
__global__ __launch_bounds__(256) void gather_gemm2_max_kernel(
    const float* __restrict__ UV, const int* __restrict__ nidx,
    const float* __restrict__ W2, const float* __restrict__ b2,
    float* __restrict__ Y, int H2) {
  __shared__ float As[32][64 + 4];
  __shared__ float Ws[32][64];
  __shared__ float red[16][64];

  const int tid = threadIdx.x;
  const int tx = tid & 15, ty = tid >> 4;
  const int p0 = blockIdx.y * 2;
  const int n0 = blockIdx.x * 64;
  const int N2 = 2 * H1;

  const int r = tid >> 2;
  const int k4g = (tid & 3) * 4;
  const int pt = p0 + (r >> 5);
  int e = r & 31;
  if (e >= kK) e = 0;
  const int j = nidx[(size_t)pt * kK + e];
  const int jglob = (pt & ~(kN - 1)) + j;
  const float* __restrict__ Urow = UV + (size_t)pt * N2;
  const float* __restrict__ Vrow = UV + (size_t)jglob * N2 + H1;

  const int wk = tid >> 6;
  const int wn = tid & 63;

  float acc[4][4] = {};

  #pragma unroll
  for (int k0 = 0; k0 < H1; k0 += 32) {
    #pragma unroll
    for (int kq = 0; kq < 2; ++kq) {
      const int kk4 = k4g + kq * 16;
      float4 u4 = *reinterpret_cast<const float4*>(Urow + k0 + kk4);
      float4 v4 = *reinterpret_cast<const float4*>(Vrow + k0 + kk4);
      As[kk4 + 0][r] = fmaxf(u4.x + v4.x, 0.f);
      As[kk4 + 1][r] = fmaxf(u4.y + v4.y, 0.f);
      As[kk4 + 2][r] = fmaxf(u4.z + v4.z, 0.f);
      As[kk4 + 3][r] = fmaxf(u4.w + v4.w, 0.f);
    }
    #pragma unroll
    for (int qq = 0; qq < 8; ++qq)
      Ws[wk + qq * 4][wn] = W2[(size_t)(k0 + wk + qq * 4) * H2 + n0 + wn];
    __syncthreads();
    #pragma unroll
    for (int kk = 0; kk < 32; ++kk) {
      float4 a4 = *reinterpret_cast<const float4*>(&As[kk][ty * 4]);
      float4 b4 = *reinterpret_cast<const float4*>(&Ws[kk][tx * 4]);
      float av[4] = {a4.x, a4.y, a4.z, a4.w};
      float bv[4] = {b4.x, b4.y, b4.z, b4.w};
      #pragma unroll
      for (int i2 = 0; i2 < 4; ++i2)
        #pragma unroll
        for (int j2 = 0; j2 < 4; ++j2)
          acc[i2][j2] = fmaf(av[i2], bv[j2], acc[i2][j2]);
    }
    __syncthreads();
  }

  #pragma unroll
  for (int j2 = 0; j2 < 4; ++j2) {
    float m = fmaxf(fmaxf(acc[0][j2], acc[1][j2]), fmaxf(acc[2][j2], acc[3][j2]));
    red[ty][tx * 4 + j2] = m;
  }
  __syncthreads();
  if (tid < 128) {
    int ptl = tid >> 6, c = tid & 63;
    float m = red[ptl * 8][c];
    #pragma unroll
    for (int qq = 1; qq < 8; ++qq) m = fmaxf(m, red[ptl * 8 + qq][c]);
    Y[(size_t)(p0 + ptl) * H2 + n0 + c] = m + b2[n0 + c];
  }
}

// ---------------- pack feW2 (1024x1024) into MFMA fragment order -----------
__global__ void pack_w2_kernel(const float* __restrict__ W2,
                               unsigned short* __restrict__ wp) {
  int e = blockIdx.x * 256 + threadIdx.x;
  if (e >= 64 * 32 * 64 * 8) return;
  int i = e & 7;
  int lane = (e >> 3) & 63;
  int ks = (e >> 9) & 31;
  int tg = e >> 14;
  int n = tg * 16 + (lane & 15);
  int k = ks * 32 + (lane >> 4) * 8 + i;
  float w = W2[(size_t)k * 1024 + n];
  unsigned short hi = bf16hi(w);
  unsigned short lo = bf16hi(w - bf16tof(hi));
  size_t base = ((size_t)(tg * 32 + ks) * 64 + lane) * 16;
  wp[base + i] = hi;
  wp[base + 8 + i] = lo;
}

// ---------------- generic pack (K x N) into MFMA fragment order ------------
__global__ void pack_w2gen_kernel(const float* __restrict__ W2,
                                  unsigned short* __restrict__ wp,
                                  int H1, int H2) {
  int e = blockIdx.x * 256 + threadIdx.x;
  int nks = H1 / 32;
  int total = (H2 / 16) * nks * 64 * 8;
  if (e >= total) return;
  int i = e & 7;
  int lane = (e >> 3) & 63;
  int rem = e >> 9;
  int ks = rem % nks;
  int tg = rem / nks;
  int n = tg * 16 + (lane & 15);
  int k = ks * 32 + (lane >> 4) * 8 + i;
  float w = W2[(size_t)k * H2 + n];
  unsigned short hi = bf16hi(w);
  unsigned short lo = bf16hi(w - bf16tof(hi));
  size_t base = ((size_t)(tg * nks + ks) * 64 + lane) * 16;
  wp[base + i] = hi;
  wp[base + 8 + i] = lo;
}

// -------- e4 gather + split-bf16 MFMA + max (H1=128, H2=128) ---------------
#define SPL8(h, l, i, val)                                        \
  { float _v = (val); unsigned short _h = bf16hi(_v);             \
    h[i] = (short)_h; l[i] = (short)bf16hi(_v - bf16tof(_h)); }

__global__ __launch_bounds__(256) void gather_mfma_max_kernel(
    const float* __restrict__ UV, const int* __restrict__ nidx,
    const unsigned short* __restrict__ wpk, const float* __restrict__ b2,
    float* __restrict__ Y) {
  const int t = threadIdx.x;
  const int l = t & 63;
  const int wv = t >> 6;
  const int pt = blockIdx.x * 4 + wv;
  const int arow = l & 15;
  const int kgrp = l >> 4;

  const int base = pt & ~(kN - 1);
  int e1 = 16 + arow;
  if (e1 >= kK) e1 = 0;
  const int j0 = base + nidx[(size_t)pt * kK + arow];
  const int j1 = base + nidx[(size_t)pt * kK + e1];
  const float* __restrict__ U  = UV + (size_t)pt * 256;
  const float* __restrict__ V0 = UV + (size_t)j0 * 256 + 128;
  const float* __restrict__ V1 = UV + (size_t)j1 * 256 + 128;

  f32x4v acc0[8], acc1[8];
  f32x4v zz = {0.f, 0.f, 0.f, 0.f};
  #pragma unroll
  for (int i = 0; i < 8; ++i) { acc0[i] = zz; acc1[i] = zz; }

  #pragma unroll
  for (int ks = 0; ks < 4; ++ks) {
    const int kb = ks * 32 + kgrp * 8;
    float4 ua = *reinterpret_cast<const float4*>(U + kb);
    float4 ub = *reinterpret_cast<const float4*>(U + kb + 4);
    float4 va = *reinterpret_cast<const float4*>(V0 + kb);
    float4 vb = *reinterpret_cast<const float4*>(V0 + kb + 4);
    short8v a0h, a0l;
    SPL8(a0h, a0l, 0, fmaxf(ua.x + va.x, 0.f));
    SPL8(a0h, a0l, 1, fmaxf(ua.y + va.y, 0.f));
    SPL8(a0h, a0l, 2, fmaxf(ua.z + va.z, 0.f));
    SPL8(a0h, a0l, 3, fmaxf(ua.w + va.w, 0.f));
    SPL8(a0h, a0l, 4, fmaxf(ub.x + vb.x, 0.f));
    SPL8(a0h, a0l, 5, fmaxf(ub.y + vb.y, 0.f));
    SPL8(a0h, a0l, 6, fmaxf(ub.z + vb.z, 0.f));
    SPL8(a0h, a0l, 7, fmaxf(ub.w + vb.w, 0.f));
    va = *reinterpret_cast<const float4*>(V1 + kb);
    vb = *reinterpret_cast<const float4*>(V1 + kb + 4);
    short8v a1h, a1l;
    SPL8(a1h, a1l, 0, fmaxf(ua.x + va.x, 0.f));
    SPL8(a1h, a1l, 1, fmaxf(ua.y + va.y, 0.f));
    SPL8(a1h, a1l, 2, fmaxf(ua.z + va.z, 0.f));
    SPL8(a1h, a1l, 3, fmaxf(ua.w + va.w, 0.f));
    SPL8(a1h, a1l, 4, fmaxf(ub.x + vb.x, 0.f));
    SPL8(a1h, a1l, 5, fmaxf(ub.y + vb.y, 0.f));
    SPL8(a1h, a1l, 6, fmaxf(ub.z + vb.z, 0.f));
    SPL8(a1h, a1l, 7, fmaxf(ub.w + vb.w, 0.f));
    #pragma unroll
    for (int tg = 0; tg < 8; ++tg) {
      const unsigned short* bp = wpk + ((size_t)(tg * 4 + ks) * 64 + l) * 16;
      short8v bh = *reinterpret_cast<const short8v*>(bp);
      short8v bl = *reinterpret_cast<const short8v*>(bp + 8);
      acc0[tg] = __builtin_amdgcn_mfma_f32_16x16x32_bf16(a0h, bh, acc0[tg], 0, 0, 0);
      acc0[tg] = __builtin_amdgcn_mfma_f32_16x16x32_bf16(a0h, bl, acc0[tg], 0, 0, 0);
      acc0[tg] = __builtin_amdgcn_mfma_f32_16x16x32_bf16(a0l, bh, acc0[tg], 0, 0, 0);
      acc1[tg] = __builtin_amdgcn_mfma_f32_16x16x32_bf16(a1h, bh, acc1[tg], 0, 0, 0);
      acc1[tg] = __builtin_amdgcn_mfma_f32_16x16x32_bf16(a1h, bl, acc1[tg], 0, 0, 0);
      acc1[tg] = __builtin_amdgcn_mfma_f32_16x16x32_bf16(a1l, bh, acc1[tg], 0, 0, 0);
    }
  }

  #pragma unroll
  for (int tg = 0; tg < 8; ++tg) {
    float m = fmaxf(fmaxf(acc0[tg][0], acc0[tg][1]),
                    fmaxf(acc0[tg][2], acc0[tg][3]));
    m = fmaxf(m, fmaxf(fmaxf(acc1[tg][0], acc1[tg][1]),
                       fmaxf(acc1[tg][2], acc1[tg][3])));
    m = fmaxf(m, __shfl_xor(m, 16));
    m = fmaxf(m, __shfl_xor(m, 32));
    if (kgrp == 0) {
      int n = tg * 16 + arow;
      Y[(size_t)pt * 128 + n] = m + b2[n];
    }
  }
}

// ------- fused fe: BOTH phases split-bf16 MFMA (R13-proven, 418 us) --------
#define FRT 16
__global__ __launch_bounds__(256) void fe_fused_kernel(
    const float* __restrict__ x4, const unsigned short* __restrict__ wpf1,
    const float* __restrict__ b1, const unsigned short* __restrict__ wpack,
    const float* __restrict__ b2, float* __restrict__ part) {
  __shared__ unsigned short xh[FRT][136];
  __shared__ unsigned short xl[FRT][136];
  __shared__ unsigned short h1h[FRT][1032];
  __shared__ unsigned short h1l[FRT][1032];
  const int tile = blockIdx.x;
  const int r0 = tile * FRT;
  const int t = threadIdx.x;

  for (int e = t; e < FRT * 32; e += 256) {
    int r = e / 32, c4 = e % 32;
    float4 v = *reinterpret_cast<const float4*>(&x4[(size_t)(r0 + r) * 128 + c4 * 4]);
    unsigned short h0 = bf16hi(v.x), h1_ = bf16hi(v.y), h2 = bf16hi(v.z), h3 = bf16hi(v.w);
    xh[r][c4 * 4 + 0] = h0; xh[r][c4 * 4 + 1] = h1_;
    xh[r][c4 * 4 + 2] = h2; xh[r][c4 * 4 + 3] = h3;
    xl[r][c4 * 4 + 0] = bf16hi(v.x - bf16tof(h0));
    xl[r][c4 * 4 + 1] = bf16hi(v.y - bf16tof(h1_));
    xl[r][c4 * 4 + 2] = bf16hi(v.z - bf16tof(h2));
    xl[r][c4 * 4 + 3] = bf16hi(v.w - bf16tof(h3));
  }
  __syncthreads();

  const int l = t & 63;
  const int wv = t >> 6;
  const int arow = l & 15;
  const int kgrp = l >> 4;

  // ---- phase 1: h1 = relu(x4@W1 + b1) via MFMA ----
  {
    short8v ahv[4], alv[4];
    #pragma unroll
    for (int ks = 0; ks < 4; ++ks) {
      ahv[ks] = *reinterpret_cast<const short8v*>(&xh[arow][ks * 32 + kgrp * 8]);
      alv[ks] = *reinterpret_cast<const short8v*>(&xl[arow][ks * 32 + kgrp * 8]);
    }
    #pragma unroll
    for (int tg = 0; tg < 16; ++tg) {
      const int tgg = wv * 16 + tg;
      f32x4v a1 = {0.f, 0.f, 0.f, 0.f};
      #pragma unroll
      for (int ks = 0; ks < 4; ++ks) {
        const unsigned short* bp = wpf1 + ((size_t)(tgg * 4 + ks) * 64 + l) * 16;
        short8v bh = *reinterpret_cast<const short8v*>(bp);
        short8v bl = *reinterpret_cast<const short8v*>(bp + 8);
        a1 = __builtin_amdgcn_mfma_f32_16x16x32_bf16(ahv[ks], bh, a1, 0, 0, 0);
        a1 = __builtin_amdgcn_mfma_f32_16x16x32_bf16(ahv[ks], bl, a1, 0, 0, 0);
        a1 = __builtin_amdgcn_mfma_f32_16x16x32_bf16(alv[ks], bh, a1, 0, 0, 0);
      }
      const int col = tgg * 16 + arow;
      const float bb = b1[col];
      #pragma unroll
      for (int i = 0; i < 4; ++i) {
        float v = fmaxf(a1[i] + bb, 0.f);
        unsigned short h = bf16hi(v);
        h1h[kgrp * 4 + i][col] = h;
        h1l[kgrp * 4 + i][col] = bf16hi(v - bf16tof(h));
      }
    }
  }
  __syncthreads();

  // ---- phase 2: split-bf16 MFMA, tg-chunked, B reg-double-buffered ----
  #pragma unroll
  for (int tc = 0; tc < 4; ++tc) {
    f32x4v accm[4];
    f32x4v zz = {0.f, 0.f, 0.f, 0.f};
    #pragma unroll
    for (int i = 0; i < 4; ++i) accm[i] = zz;

    const int tgb = wv * 16 + tc * 4;
    short8v bhC[4], blC[4], bhN[4], blN[4];
    #pragma unroll
    for (int tt = 0; tt < 4; ++tt) {
      const unsigned short* bp = wpack + ((size_t)((tgb + tt) * 32 + 0) * 64 + l) * 16;
      bhC[tt] = *reinterpret_cast<const short8v*>(bp);
      blC[tt] = *reinterpret_cast<const short8v*>(bp + 8);
    }
    for (int ks = 0; ks < 32; ++ks) {
      if (ks < 31) {
        #pragma unroll
        for (int tt = 0; tt < 4; ++tt) {
          const unsigned short* bp =
              wpack + ((size_t)((tgb + tt) * 32 + ks + 1) * 64 + l) * 16;
          bhN[tt] = *reinterpret_cast<const short8v*>(bp);
          blN[tt] = *reinterpret_cast<const short8v*>(bp + 8);
        }
      }
      const int kb = ks * 32 + kgrp * 8;
      short8v ah = *reinterpret_cast<const short8v*>(&h1h[arow][kb]);
      short8v al = *reinterpret_cast<const short8v*>(&h1l[arow][kb]);
      #pragma unroll
      for (int tt = 0; tt < 4; ++tt) {
        accm[tt] = __builtin_amdgcn_mfma_f32_16x16x32_bf16(ah, bhC[tt], accm[tt], 0, 0, 0);
        accm[tt] = __builtin_amdgcn_mfma_f32_16x16x32_bf16(ah, blC[tt], accm[tt], 0, 0, 0);
        accm[tt] = __builtin_amdgcn_mfma_f32_16x16x32_bf16(al, bhC[tt], accm[tt], 0, 0, 0);
      }
      #pragma unroll
      for (int tt = 0; tt < 4; ++tt) { bhC[tt] = bhN[tt]; blC[tt] = blN[tt]; }
    }
    #pragma unroll
    for (int tt = 0; tt < 4; ++tt) {
      float m = fmaxf(fmaxf(accm[tt][0], accm[tt][1]),
                      fmaxf(accm[tt][2], accm[tt][3]));
      m = fmaxf(m, __shfl_xor(m, 16));
      m = fmaxf(m, __shfl_xor(m, 32));
      if (kgrp == 0) {
        int n = (wv * 16 + tc * 4 + tt) * 16 + arow;
        part[(size_t)tile * 1024 + n] = m + b2[n];
      }
    }
  }
}

// --------------------------- reduce partials -> g ---------------------------
__global__ void reduce_g_kernel(const float* __restrict__ part, float* __restrict__ g) {
  int e = blockIdx.x * 256 + threadIdx.x;
  if (e >= kB * 1024) return;
  int b = e / 1024, c = e % 1024;
  const int tilesPerBatch = kN / FRT;  // 256
  const float* p = part + (size_t)b * tilesPerBatch * 1024 + c;
  float m = -INFINITY;
  for (int t = 0; t < tilesPerBatch; ++t) m = fmaxf(m, p[(size_t)t * 1024]);
  g[e] = m;
}

// --------------- per-batch head-0 g-contribution: gvec = g@W[326:]+b -------
__global__ void ghead_kernel(const float* __restrict__ g,
                             const float* __restrict__ h0W,
                             const float* __restrict__ h0b,
                             float* __restrict__ gvec) {
  const int b = blockIdx.x;
  const int n = threadIdx.x;
  float acc = h0b[n];
  const float* gb = g + (size_t)b * 1024;
  for (int k = 0; k < 1024; ++k)
    acc = fmaf(gb[k], h0W[(size_t)(326 + k) * 256 + n], acc);
  gvec[b * 256 + n] = acc;
}

// ---------- head MFMA GEMM: out = act(A@B + bias), A fp32 chunk-local ------
template <int KD, int NN>
__global__ __launch_bounds__(256) void head_mfma_kernel(
    const float* __restrict__ A, const unsigned short* __restrict__ bpk,
    const float* __restrict__ bias, float* __restrict__ out, int relu) {
  constexpr int NKS = KD / 32;
  __shared__ unsigned short ah[32][KD + 8];
  __shared__ unsigned short al[32][KD + 8];
  const int t = threadIdx.x;
  const int m0 = blockIdx.y * 32;
  const int n0 = blockIdx.x * 128;

  for (int e = t; e < 32 * (KD / 4); e += 256) {
    int r = e / (KD / 4), c4 = e % (KD / 4);
    float4 v = *reinterpret_cast<const float4*>(&A[(size_t)(m0 + r) * KD + c4 * 4]);
    unsigned short h0 = bf16hi(v.x), h1 = bf16hi(v.y), h2 = bf16hi(v.z), h3 = bf16hi(v.w);
    ah[r][c4 * 4 + 0] = h0; ah[r][c4 * 4 + 1] = h1;
    ah[r][c4 * 4 + 2] = h2; ah[r][c4 * 4 + 3] = h3;
    al[r][c4 * 4 + 0] = bf16hi(v.x - bf16tof(h0));
    al[r][c4 * 4 + 1] = bf16hi(v.y - bf16tof(h1));
    al[r][c4 * 4 + 2] = bf16hi(v.z - bf16tof(h2));
    al[r][c4 * 4 + 3] = bf16hi(v.w - bf16tof(h3));
  }
  __syncthreads();

  const int l = t & 63;
  const int wv = t >> 6;
  const int rf = wv >> 1;
  const int ch = wv & 1;
  const int arow = rf * 16 + (l & 15);
  const int kgrp = l >> 4;

  f32x4v acc[4];
  f32x4v zz = {0.f, 0.f, 0.f, 0.f};
  #pragma unroll
  for (int i = 0; i < 4; ++i) acc[i] = zz;

  for (int ks = 0; ks < NKS; ++ks) {
    const int kb = ks * 32 + kgrp * 8;
    short8v a_h = *reinterpret_cast<const short8v*>(&ah[arow][kb]);
    short8v a_l = *reinterpret_cast<const short8v*>(&al[arow][kb]);
    #pragma unroll
    for (int tg = 0; tg < 4; ++tg) {
      const int tgg = n0 / 16 + ch * 4 + tg;
      const unsigned short* bp = bpk + ((size_t)(tgg * NKS + ks) * 64 + l) * 16;
      short8v bh = *reinterpret_cast<const short8v*>(bp);
      short8v bl = *reinterpret_cast<const short8v*>(bp + 8);
      acc[tg] = __builtin_amdgcn_mfma_f32_16x16x32_bf16(a_h, bh, acc[tg], 0, 0, 0);
      acc[tg] = __builtin_amdgcn_mfma_f32_16x16x32_bf16(a_h, bl, acc[tg], 0, 0, 0);
      acc[tg] = __builtin_amdgcn_mfma_f32_16x16x32_bf16(a_l, bh, acc[tg], 0, 0, 0);
    }
  }

  #pragma unroll
  for (int tg = 0; tg < 4; ++tg) {
    int col = n0 + (ch * 4 + tg) * 16 + (l & 15);
    float bb = bias[col];
    #pragma unroll
    for (int i = 0; i < 4; ++i) {
      int row = m0 + rf * 16 + kgrp * 4 + i;
      float v = acc[tg][i] + bb;
      if (relu) v = fmaxf(v, 0.f);
      out[(size_t)row * NN + col] = v;
    }
  }
}

// ------------------------------- GEMM --------------------------------------
struct FeatSrc {
  const float* x0; const float* x1; const float* x2;
  const float* x3; const float* x4; const float* g;
};

template <int ASRC>
__device__ __forceinline__ float a_fetch(const float* __restrict__ A,
                                         const FeatSrc& fs, int row, int k, int Kd) {
  if constexpr (ASRC == 0) {
    return A[(size_t)row * Kd + k];
  } else {
    if (k < 6)        return fs.x0[(size_t)row * 8 + k];
    else if (k < 70)  return fs.x1[(size_t)row * 64 + (k - 6)];
    else if (k < 134) return fs.x2[(size_t)row * 64 + (k - 70)];
    else if (k < 198) return fs.x3[(size_t)row * 64 + (k - 134)];
    else              return fs.x4[(size_t)row * 128 + (k - 198)];
  }
}

#define GBM 64
#define GBN 64
#define GBK 16

template <int ASRC>
__global__ __launch_bounds__(256) void gemm_kernel(
    const float* __restrict__ A, FeatSrc fs,
    const float* __restrict__ Bm, const float* __restrict__ bias,
    float* __restrict__ out, int row0, int Nn, int Kd, int relu, int biasb) {
  __shared__ float As[GBK][GBM + 4];
  __shared__ float Bs[GBK][GBN];

  const int tid = threadIdx.x;
  const int tx = tid % 16, ty = tid / 16;
  const int m0 = blockIdx.y * GBM;
  const int n0 = blockIdx.x * GBN;

  float acc[4][4] = {};

  for (int k0 = 0; k0 < Kd; k0 += GBK) {
    #pragma unroll
    for (int r = 0; r < 4; ++r) {
      int ee = tid + r * 256;
      int ar = ee / GBK, ak = ee % GBK;
      int kk = k0 + ak;
      float v = 0.f;
      if (kk < Kd) {
        int arow = (ASRC == 1) ? (row0 + m0 + ar) : (m0 + ar);
        v = a_fetch<ASRC>(A, fs, arow, kk, Kd);
      }
      As[ak][ar] = v;
    }
    #pragma unroll
    for (int r = 0; r < 4; ++r) {
      int ee = tid + r * 256;
      int bk = ee / GBN, bn = ee % GBN;
      int kk = k0 + bk;
      float v = 0.f;
      if (kk < Kd && (n0 + bn) < Nn) v = Bm[(size_t)kk * Nn + n0 + bn];
      Bs[bk][bn] = v;
    }
    __syncthreads();
    #pragma unroll
    for (int kk = 0; kk < GBK; ++kk) {
      float4 a4 = *reinterpret_cast<const float4*>(&As[kk][ty * 4]);
      float4 b4 = *reinterpret_cast<const float4*>(&Bs[kk][tx * 4]);
      float av[4] = {a4.x, a4.y, a4.z, a4.w};
      float bv[4] = {b4.x, b4.y, b4.z, b4.w};
      #pragma unroll
      for (int i2 = 0; i2 < 4; ++i2)
        #pragma unroll
        for (int j2 = 0; j2 < 4; ++j2)
          acc[i2][j2] = fmaf(av[i2], bv[j2], acc[i2][j2]);
    }
    __syncthreads();
  }

  #pragma unroll
  for (int j2 = 0; j2 < 4; ++j2) {
    int n = n0 + tx * 4 + j2;
    if (n >= Nn) continue;
    #pragma unroll
    for (int i2 = 0; i2 < 4; ++i2) {
      float bb;
      if (biasb) {
        int grow = row0 + m0 + ty * 4 + i2;
        bb = bias[(size_t)(grow >> 12) * 256 + n];
      } else {
        bb = bias ? bias[n] : 0.f;
      }
      float v = acc[i2][j2] + bb;
      if (relu) v = fmaxf(v, 0.f);
      out[(size_t)(m0 + ty * 4 + i2) * Nn + n] = v;
    }
  }
}

// ------------------------------ log_softmax --------------------------------
__global__ void log_softmax_kernel(const float* __restrict__ logits,
                                   float* __restrict__ out, int row0) {
  int r = blockIdx.x * 256 + threadIdx.x;
  if (r >= kCH) return;
  const float* lp = logits + (size_t)r * 13;
  float v[13];
  float m = -INFINITY;
  #pragma unroll
  for (int c = 0; c < 13; ++c) { v[c] = lp[c]; m = fmaxf(m, v[c]); }
  float s = 0.f;
  #pragma unroll
  for (int c = 0; c < 13; ++c) s += expf(v[c] - m);
  float ls = logf(s);
  float* op = out + (size_t)(row0 + r) * 13;
  #pragma unroll
  for (int c = 0; c < 13; ++c) op[c] = v[c] - m - ls;
}

// ------------------------------- launch ------------------------------------
static void run_knn(const float* X, const float* nrm, float* Dbuf, int* nidx,
                    int CS, hipStream_t stream) {
  for (int b = 0; b < kB; ++b) {
    for (int h = 0; h < kN / kDQ; ++h) {
      if (CS == 8)
        dist_gemm_kernel<8><<<dim3(kN / 64, kDQ / 64), 256, 0, stream>>>(
            X + (size_t)b * kN * 8, nrm + (size_t)b * kN, Dbuf, h * kDQ);
      else
        dist_gemm_kernel<64><<<dim3(kN / 64, kDQ / 64), 256, 0, stream>>>(
            X + (size_t)b * kN * 64, nrm + (size_t)b * kN, Dbuf, h * kDQ);
      knn_select_kernel<<<kDQ / 4, 256, 0, stream>>>(Dbuf, nidx,
                                                     b * kN + h * kDQ);
    }
  }
}

extern "C" void kernel_launch(void* const* d_in, const int* in_sizes, int n_in,
                              void* d_out, int out_size, void* d_ws, size_t ws_size,
                              hipStream_t stream) {
  const float* x    = (const float*)d_in[0];
  const float* pos  = (const float*)d_in[1];
  const float* e1W1 = (const float*)d_in[2];
  const float* e1b1 = (const float*)d_in[3];
  const float* e1W2 = (const float*)d_in[4];
  const float* e1b2 = (const float*)d_in[5];
  const float* e2W1 = (const float*)d_in[6];
  const float* e2b1 = (const float*)d_in[7];
  const float* e2W2 = (const float*)d_in[8];
  const float* e2b2 = (const float*)d_in[9];
  const float* e3W1 = (const float*)d_in[10];
  const float* e3b1 = (const float*)d_in[11];
  const float* e3W2 = (const float*)d_in[12];
  const float* e3b2 = (const float*)d_in[13];
  const float* e4W1 = (const float*)d_in[14];
  const float* e4b1 = (const float*)d_in[15];
  const float* e4W2 = (const float*)d_in[16];
  const float* e4b2 = (const float*)d_in[17];
  const float* feW1 = (const float*)d_in[18];
  const float* feb1 = (const float*)d_in[19];
  const float* feW2 = (const float*)d_in[20];
  const float* feb2 = (const float*)d_in[21];
  const float* h0W  = (const float*)d_in[22];
  const float* h0b  = (const float*)d_in[23];
  const float* h1W  = (const float*)d_in[24];
  const float* h1b  = (const float*)d_in[25];
  const float* h2W  = (const float*)d_in[26];
  const float* h2b  = (const float*)d_in[27];
  const float* h3W  = (const float*)d_in[28];
  const float* h3b  = (const float*)d_in[29];

  float* W = (float*)d_ws;
  size_t off = 0;
  float* x0p  = W + off; off += (size_t)kBN * 8;
  float* x1   = W + off; off += (size_t)kBN * 64;
  float* x2   = W + off; off += (size_t)kBN * 64;
  float* x3   = W + off; off += (size_t)kBN * 64;
  float* x4   = W + off; off += (size_t)kBN * 128;
  float* gmax = W + off; off += (size_t)kB * 1024;
  float* gvec = W + off; off += (size_t)kB * 256;
  float* nrm  = W + off; off += (size_t)kBN;
  int*   nidx = (int*)(W + off); off += (size_t)kBN * kK;
  float* wu   = W + off; off += (size_t)64 * 256;
  float* b1e  = W + off; off += 256;
  unsigned short* wpack = (unsigned short*)(W + off); off += (size_t)1048576; // 4MB
  unsigned short* wpk4  = (unsigned short*)(W + off); off += (size_t)16384;   // 64KB
  unsigned short* wph1  = (unsigned short*)(W + off); off += (size_t)65536;   // 256KB
  unsigned short* wph2  = (unsigned short*)(W + off); off += (size_t)32768;   // 128KB
  unsigned short* wpf1  = (unsigned short*)(W + off); off += (size_t)131072;  // 512KB
  // transient union: D chunk (32MB) / uv (<=33.5MB) / fe part / head bufs
  float* trans = W + off;
  float* Dbuf = trans;
  float* uv   = trans;
  float* part = trans;
  float* ping = trans;
  float* pong = ping + (size_t)kCH * 256;
  float* h128 = pong + (size_t)kCH * 256;
  float* lgts = h128 + (size_t)kCH * 128;

  FeatSrc fs{x0p, x1, x2, x3, x4, gmax};

  concat_x0_kernel<<<(kBN * 8 + 255) / 256, 256, 0, stream>>>(x, pos, x0p);

  // ---- edge conv 1: C=6 (CS=8), H1=64, H2=64 ----
  norms_kernel<6, 8><<<(kBN + 255) / 256, 256, 0, stream>>>(x0p, nrm);
  run_knn(x0p, nrm, Dbuf, nidx, 8, stream);
  prep_uv_kernel<<<(8 * 128 + 255) / 256, 256, 0, stream>>>(e1W1, e1b1, wu, b1e, 6, 64, 8);
  gemm_kernel<0><<<dim3(128 / GBN, kBN / GBM), 256, 0, stream>>>(
      x0p, fs, wu, b1e, uv, 0, 128, 8, 0, 0);
  gather_gemm2_max_kernel<64><<<dim3(1, kBN / 2), 256, 0, stream>>>(
      uv, nidx, e1W2, e1b2, x1, 64);

  // ---- edge conv 2: C=64, H1=64, H2=64 ----
  norms_kernel<64, 64><<<(kBN + 255) / 256, 256, 0, stream>>>(x1, nrm);
  run_knn(x1, nrm, Dbuf, nidx, 64, stream);
  prep_uv_kernel<<<(64 * 128 + 255) / 256, 256, 0, stream>>>(e2W1, e2b1, wu, b1e, 64, 64, 64);
  gemm_kernel<0><<<dim3(128 / GBN, kBN / GBM), 256, 0, stream>>>(
      x1, fs, wu, b1e, uv, 0, 128, 64, 0, 0);
  gather_gemm2_max_kernel<64><<<dim3(1, kBN / 2), 256, 0, stream>>>(
      uv, nidx, e2W2, e2b2, x2, 64);

  // ---- edge conv 3 ----
  norms_kernel<64, 64><<<(kBN + 255) / 256, 256, 0, stream>>>(x2, nrm);
  run_knn(x2, nrm, Dbuf, nidx, 64, stream);
  prep_uv_kernel<<<(64 * 128 + 255) / 256, 256, 0, stream>>>(e3W1, e3b1, wu, b1e, 64, 64, 64);
  gemm_kernel<0><<<dim3(128 / GBN, kBN / GBM), 256, 0, stream>>>(
      x2, fs, wu, b1e, uv, 0, 128, 64, 0, 0);
  gather_gemm2_max_kernel<64><<<dim3(1, kBN / 2), 256, 0, stream>>>(
      uv, nidx, e3W2, e3b2, x3, 64);

  // ---- edge conv 4: C=64, H1=128, H2=128 (MFMA gather) ----
  norms_kernel<64, 64><<<(kBN + 255) / 256, 256, 0, stream>>>(x3, nrm);
  run_knn(x3, nrm, Dbuf, nidx, 64, stream);
  prep_uv_kernel<<<(64 * 256 + 255) / 256, 256, 0, stream>>>(e4W1, e4b1, wu, b1e, 64, 128, 64);
  gemm_kernel<0><<<dim3(256 / GBN, kBN / GBM), 256, 0, stream>>>(
      x3, fs, wu, b1e, uv, 0, 256, 64, 0, 0);
  pack_w2gen_kernel<<<64, 256, 0, stream>>>(e4W2, wpk4, 128, 128);
  gather_mfma_max_kernel<<<kBN / 4, 256, 0, stream>>>(uv, nidx, wpk4, e4b2, x4);

  // ---- fe fused (both phases MFMA) + global max + ghead ----
  pack_w2_kernel<<<4096, 256, 0, stream>>>(feW2, wpack);
  pack_w2gen_kernel<<<512, 256, 0, stream>>>(feW1, wpf1, 128, 1024);
  fe_fused_kernel<<<kBN / FRT, 256, 0, stream>>>(x4, wpf1, feb1, wpack, feb2, part);
  reduce_g_kernel<<<(kB * 1024 + 255) / 256, 256, 0, stream>>>(part, gmax);
  ghead_kernel<<<kB, 256, 0, stream>>>(gmax, h0W, h0b, gvec);

  // ---- pack head weights for MFMA (h1: 256x256, h2: 256x128) ----
  pack_w2gen_kernel<<<(16 * 8 * 512 + 255) / 256, 256, 0, stream>>>(h1W, wph1, 256, 256);
  pack_w2gen_kernel<<<(8 * 8 * 512 + 255) / 256, 256, 0, stream>>>(h2W, wph2, 256, 128);

  // ---- head, chunked over rows ----
  for (int c = 0; c < kBN / kCH; ++c) {
    int row0 = c * kCH;
    dim3 gh0(256 / GBN, kCH / GBM);
    gemm_kernel<1><<<gh0, 256, 0, stream>>>(nullptr, fs, h0W, gvec, ping, row0, 256, 326, 1, 1);
    head_mfma_kernel<256, 256><<<dim3(2, kCH / 32), 256, 0, stream>>>(
        ping, wph1, h1b, pong, 1);
    head_mfma_kernel<256, 128><<<dim3(1, kCH / 32), 256, 0, stream>>>(
        pong, wph2, h2b, h128, 1);
    dim3 gh3(1, kCH / GBM);
    gemm_kernel<0><<<gh3, 256, 0, stream>>>(h128, fs, h3W, h3b, lgts, row0, 13, 128, 0, 0);
    log_softmax_kernel<<<(kCH + 255) / 256, 256, 0, stream>>>(lgts, (float*)d_out, row0);
  }
}

// Round 17
// 3888.853 us; speedup vs baseline: 1.4070x; 1.3287x over previous
//
#include <hip/hip_runtime.h>
#include <math.h>

#define kB 8
#define kN 4096
#define kBN (kB * kN)
#define kK 30
#define kCH 8192   // head row-chunk

typedef __attribute__((ext_vector_type(8))) short short8v;
typedef __attribute__((ext_vector_type(4))) float f32x4v;

__device__ __forceinline__ unsigned short bf16hi(float a) {
  union { float f; unsigned u; } v; v.f = a;
  unsigned r = v.u + 0x7FFF + ((v.u >> 16) & 1);
  return (unsigned short)(r >> 16);
}
__device__ __forceinline__ float bf16tof(unsigned short h) {
  union { float f; unsigned u; } v; v.u = ((unsigned)h) << 16;
  return v.f;
}

// ----------------------------- concat x0 (padded to 8 ch) -----------------
__global__ void concat_x0_kernel(const float* __restrict__ x,
                                 const float* __restrict__ pos,
                                 float* __restrict__ x0p) {
  int e = blockIdx.x * 256 + threadIdx.x;
  if (e >= kBN * 8) return;
  int p = e / 8, c = e % 8;
  float v = 0.f;
  if (c < 3) v = x[(size_t)p * 3 + c];
  else if (c < 6) v = pos[(size_t)p * 3 + (c - 3)];
  x0p[e] = v;
}

// ------------------------------ norms ------------------------------------
template <int C, int CS>
__global__ void norms_kernel(const float* __restrict__ X, float* __restrict__ nrm) {
  int p = blockIdx.x * 256 + threadIdx.x;
  if (p >= kBN) return;
  const float* xp = X + (size_t)p * CS;
  float s = 0.f;
  for (int c = 0; c < C; ++c) s = fmaf(xp[c], xp[c], s);
  nrm[p] = s;
}

// --------------------------- kNN: distance GEMM ----------------------------
template <int CS>
__global__ __launch_bounds__(256) void dist_gemm_kernel(
    const float* __restrict__ X, const float* __restrict__ nrm,
    float* __restrict__ D, int i0) {
  __shared__ float As[CS][64 + 4];
  __shared__ float Bs[CS][64 + 4];
  const int tid = threadIdx.x;
  const int tx = tid & 15, ty = tid >> 4;
  const int rI = i0 + blockIdx.y * 64;
  const int cJ = blockIdx.x * 64;

  constexpr int QUADS = CS / 4;
  for (int e = tid; e < 64 * QUADS; e += 256) {
    int r = e & 63, q = e >> 6;
    float4 v = *reinterpret_cast<const float4*>(X + (size_t)(rI + r) * CS + q * 4);
    As[q * 4 + 0][r] = v.x; As[q * 4 + 1][r] = v.y;
    As[q * 4 + 2][r] = v.z; As[q * 4 + 3][r] = v.w;
  }
  for (int e = tid; e < 64 * QUADS; e += 256) {
    int r = e & 63, q = e >> 6;
    float4 v = *reinterpret_cast<const float4*>(X + (size_t)(cJ + r) * CS + q * 4);
    Bs[q * 4 + 0][r] = v.x; Bs[q * 4 + 1][r] = v.y;
    Bs[q * 4 + 2][r] = v.z; Bs[q * 4 + 3][r] = v.w;
  }
  __syncthreads();

  float acc[4][4] = {};
  #pragma unroll
  for (int k = 0; k < CS; ++k) {
    float4 a4 = *reinterpret_cast<const float4*>(&As[k][ty * 4]);
    float4 b4 = *reinterpret_cast<const float4*>(&Bs[k][tx * 4]);
    float av[4] = {a4.x, a4.y, a4.z, a4.w};
    float bv[4] = {b4.x, b4.y, b4.z, b4.w};
    #pragma unroll
    for (int i2 = 0; i2 < 4; ++i2)
      #pragma unroll
      for (int j2 = 0; j2 < 4; ++j2)
        acc[i2][j2] = fmaf(av[i2], bv[j2], acc[i2][j2]);
  }

  float ni[4], nj[4];
  #pragma unroll
  for (int i2 = 0; i2 < 4; ++i2) ni[i2] = nrm[rI + ty * 4 + i2];
  #pragma unroll
  for (int j2 = 0; j2 < 4; ++j2) nj[j2] = nrm[cJ + tx * 4 + j2];

  #pragma unroll
  for (int i2 = 0; i2 < 4; ++i2) {
    float4 o;
    o.x = fmaf(2.f, acc[i2][0], -ni[i2]) - nj[0];
    o.y = fmaf(2.f, acc[i2][1], -ni[i2]) - nj[1];
    o.z = fmaf(2.f, acc[i2][2], -ni[i2]) - nj[2];
    o.w = fmaf(2.f, acc[i2][3], -ni[i2]) - nj[3];
    *reinterpret_cast<float4*>(
        &D[(size_t)(blockIdx.y * 64 + ty * 4 + i2) * kN + cJ + tx * 4]) = o;
  }
}

// --------------------------- kNN: selection --------------------------------
__global__ __launch_bounds__(256) void knn_select_kernel(
    const float* __restrict__ D, int* __restrict__ idx_out, int qbase) {
  const int w = threadIdx.x >> 6;
  const int l = threadIdx.x & 63;
  const int q = blockIdx.x * 4 + w;
  const float* __restrict__ row = D + (size_t)q * kN;

  float d[64];
  #pragma unroll
  for (int m = 0; m < 64; ++m) d[m] = row[m * 64 + l];

  float gv[4];
  int gm[4];
  #pragma unroll
  for (int g = 0; g < 4; ++g) {
    float bv = -INFINITY;
    int bm = g * 16;
    #pragma unroll
    for (int mm = 0; mm < 16; ++mm) {
      const int m = g * 16 + mm;
      if (d[m] > bv) { bv = d[m]; bm = m; }
    }
    gv[g] = bv;
    gm[g] = bm;
  }

  int myout = 0;
  for (int k = 0; k < kK; ++k) {
    float cv = gv[0];
    int cm = gm[0];
    if (gv[1] > cv) { cv = gv[1]; cm = gm[1]; }
    if (gv[2] > cv) { cv = gv[2]; cm = gm[2]; }
    if (gv[3] > cv) { cv = gv[3]; cm = gm[3]; }
    int cj = cm * 64 + l;
    #pragma unroll
    for (int off = 32; off > 0; off >>= 1) {
      float ov = __shfl_xor(cv, off);
      int oj = __shfl_xor(cj, off);
      if (ov > cv || (ov == cv && oj < cj)) { cv = ov; cj = oj; }
    }
    if (l == k) myout = cj;
    if ((cj & 63) == l) {
      const int om = cj >> 6;
      const int g = om >> 4;
#define RESCAN_GROUP(G)                                                  \
  {                                                                      \
    float nv = -INFINITY;                                                \
    int nm = (G) * 16;                                                   \
    _Pragma("unroll") for (int mm = 0; mm < 16; ++mm) {                  \
      const int m = (G) * 16 + mm;                                       \
      float dd = (m == om) ? -INFINITY : d[m];                           \
      d[m] = dd;                                                         \
      if (dd > nv) { nv = dd; nm = m; }                                  \
    }                                                                    \
    gv[G] = nv;                                                          \
    gm[G] = nm;                                                          \
  }
      if (g == 0) RESCAN_GROUP(0)
      else if (g == 1) RESCAN_GROUP(1)
      else if (g == 2) RESCAN_GROUP(2)
      else RESCAN_GROUP(3)
#undef RESCAN_GROUP
    }
  }
  if (l < kK) idx_out[(size_t)(qbase + q) * kK + l] = myout;
}

// -------------------- EdgeConv via U/V decomposition -----------------------
__global__ void prep_uv_kernel(const float* __restrict__ W1,
                               const float* __restrict__ b1,
                               float* __restrict__ wu, float* __restrict__ b1e,
                               int C, int H1, int CS) {
  const int n2 = 2 * H1;
  int e = blockIdx.x * 256 + threadIdx.x;
  if (e < n2) b1e[e] = (e < H1) ? b1[e] : 0.f;
  if (e >= CS * n2) return;
  int c = e / n2, n = e % n2;
  float v;
  if (c >= C) v = 0.f;
  else if (n < H1) v = W1[(size_t)c * H1 + n] - W1[(size_t)(C + c) * H1 + n];
  else v = W1[(size_t)(C + c) * H1 + (n - H1)];
  wu[e] = v;
}

// gather + GEMM2 + max (fp32, 2 points x 32 edges, K-chunk 32) — e1-e3
template <int H1>
__global__ __launch_bounds__(256) void gather_gemm2_max_kernel(
    const float* __restrict__ UV, const int* __restrict__ nidx,
    const float* __restrict__ W2, const float* __restrict__ b2,
    float* __restrict__ Y, int H2) {
  __shared__ float As[32][64 + 4];
  __shared__ float Ws[32][64];
  __shared__ float red[16][64];

  const int tid = threadIdx.x;
  const int tx = tid & 15, ty = tid >> 4;
  const int p0 = blockIdx.y * 2;
  const int n0 = blockIdx.x * 64;
  const int N2 = 2 * H1;

  const int r = tid >> 2;
  const int k4g = (tid & 3) * 4;
  const int pt = p0 + (r >> 5);
  int e = r & 31;
  if (e >= kK) e = 0;
  const int j = nidx[(size_t)pt * kK + e];
  const int jglob = (pt & ~(kN - 1)) + j;
  const float* __restrict__ Urow = UV + (size_t)pt * N2;
  const float* __restrict__ Vrow = UV + (size_t)jglob * N2 + H1;

  const int wk = tid >> 6;
  const int wn = tid & 63;

  float acc[4][4] = {};

  #pragma unroll
  for (int k0 = 0; k0 < H1; k0 += 32) {
    #pragma unroll
    for (int kq = 0; kq < 2; ++kq) {
      const int kk4 = k4g + kq * 16;
      float4 u4 = *reinterpret_cast<const float4*>(Urow + k0 + kk4);
      float4 v4 = *reinterpret_cast<const float4*>(Vrow + k0 + kk4);
      As[kk4 + 0][r] = fmaxf(u4.x + v4.x, 0.f);
      As[kk4 + 1][r] = fmaxf(u4.y + v4.y, 0.f);
      As[kk4 + 2][r] = fmaxf(u4.z + v4.z, 0.f);
      As[kk4 + 3][r] = fmaxf(u4.w + v4.w, 0.f);
    }
    #pragma unroll
    for (int qq = 0; qq < 8; ++qq)
      Ws[wk + qq * 4][wn] = W2[(size_t)(k0 + wk + qq * 4) * H2 + n0 + wn];
    __syncthreads();
    #pragma unroll
    for (int kk = 0; kk < 32; ++kk) {
      float4 a4 = *reinterpret_cast<const float4*>(&As[kk][ty * 4]);
      float4 b4 = *reinterpret_cast<const float4*>(&Ws[kk][tx * 4]);
      float av[4] = {a4.x, a4.y, a4.z, a4.w};
      float bv[4] = {b4.x, b4.y, b4.z, b4.w};
      #pragma unroll
      for (int i2 = 0; i2 < 4; ++i2)
        #pragma unroll
        for (int j2 = 0; j2 < 4; ++j2)
          acc[i2][j2] = fmaf(av[i2], bv[j2], acc[i2][j2]);
    }
    __syncthreads();
  }

  #pragma unroll
  for (int j2 = 0; j2 < 4; ++j2) {
    float m = fmaxf(fmaxf(acc[0][j2], acc[1][j2]), fmaxf(acc[2][j2], acc[3][j2]));
    red[ty][tx * 4 + j2] = m;
  }
  __syncthreads();
  if (tid < 128) {
    int ptl = tid >> 6, c = tid & 63;
    float m = red[ptl * 8][c];
    #pragma unroll
    for (int qq = 1; qq < 8; ++qq) m = fmaxf(m, red[ptl * 8 + qq][c]);
    Y[(size_t)(p0 + ptl) * H2 + n0 + c] = m + b2[n0 + c];
  }
}

// ---------------- pack feW2 (1024x1024) into MFMA fragment order -----------
__global__ void pack_w2_kernel(const float* __restrict__ W2,
                               unsigned short* __restrict__ wp) {
  int e = blockIdx.x * 256 + threadIdx.x;
  if (e >= 64 * 32 * 64 * 8) return;
  int i = e & 7;
  int lane = (e >> 3) & 63;
  int ks = (e >> 9) & 31;
  int tg = e >> 14;
  int n = tg * 16 + (lane & 15);
  int k = ks * 32 + (lane >> 4) * 8 + i;
  float w = W2[(size_t)k * 1024 + n];
  unsigned short hi = bf16hi(w);
  unsigned short lo = bf16hi(w - bf16tof(hi));
  size_t base = ((size_t)(tg * 32 + ks) * 64 + lane) * 16;
  wp[base + i] = hi;
  wp[base + 8 + i] = lo;
}

// ---------------- generic pack (K x N) into MFMA fragment order ------------
__global__ void pack_w2gen_kernel(const float* __restrict__ W2,
                                  unsigned short* __restrict__ wp,
                                  int H1, int H2) {
  int e = blockIdx.x * 256 + threadIdx.x;
  int nks = H1 / 32;
  int total = (H2 / 16) * nks * 64 * 8;
  if (e >= total) return;
  int i = e & 7;
  int lane = (e >> 3) & 63;
  int rem = e >> 9;
  int ks = rem % nks;
  int tg = rem / nks;
  int n = tg * 16 + (lane & 15);
  int k = ks * 32 + (lane >> 4) * 8 + i;
  float w = W2[(size_t)k * H2 + n];
  unsigned short hi = bf16hi(w);
  unsigned short lo = bf16hi(w - bf16tof(hi));
  size_t base = ((size_t)(tg * nks + ks) * 64 + lane) * 16;
  wp[base + i] = hi;
  wp[base + 8 + i] = lo;
}

// ---------------- pack h0W rows 0..325 (zero-pad to K=352), N=256 ----------
__global__ void pack_h0_kernel(const float* __restrict__ W,
                               unsigned short* __restrict__ wp) {
  int e = blockIdx.x * 256 + threadIdx.x;
  const int nks = 11;  // 352/32
  int total = 16 * nks * 64 * 8;
  if (e >= total) return;
  int i = e & 7;
  int lane = (e >> 3) & 63;
  int rem = e >> 9;
  int ks = rem % nks;
  int tg = rem / nks;
  int n = tg * 16 + (lane & 15);
  int k = ks * 32 + (lane >> 4) * 8 + i;
  float w = (k < 326) ? W[(size_t)k * 256 + n] : 0.f;
  unsigned short hi = bf16hi(w);
  unsigned short lo = bf16hi(w - bf16tof(hi));
  size_t base = ((size_t)(tg * nks + ks) * 64 + lane) * 16;
  wp[base + i] = hi;
  wp[base + 8 + i] = lo;
}

// -------- e4 gather + split-bf16 MFMA + max (H1=128, H2=128) ---------------
#define SPL8(h, l, i, val)                                        \
  { float _v = (val); unsigned short _h = bf16hi(_v);             \
    h[i] = (short)_h; l[i] = (short)bf16hi(_v - bf16tof(_h)); }

__global__ __launch_bounds__(256) void gather_mfma_max_kernel(
    const float* __restrict__ UV, const int* __restrict__ nidx,
    const unsigned short* __restrict__ wpk, const float* __restrict__ b2,
    float* __restrict__ Y) {
  const int t = threadIdx.x;
  const int l = t & 63;
  const int wv = t >> 6;
  const int pt = blockIdx.x * 4 + wv;
  const int arow = l & 15;
  const int kgrp = l >> 4;

  const int base = pt & ~(kN - 1);
  int e1 = 16 + arow;
  if (e1 >= kK) e1 = 0;
  const int j0 = base + nidx[(size_t)pt * kK + arow];
  const int j1 = base + nidx[(size_t)pt * kK + e1];
  const float* __restrict__ U  = UV + (size_t)pt * 256;
  const float* __restrict__ V0 = UV + (size_t)j0 * 256 + 128;
  const float* __restrict__ V1 = UV + (size_t)j1 * 256 + 128;

  f32x4v acc0[8], acc1[8];
  f32x4v zz = {0.f, 0.f, 0.f, 0.f};
  #pragma unroll
  for (int i = 0; i < 8; ++i) { acc0[i] = zz; acc1[i] = zz; }

  #pragma unroll
  for (int ks = 0; ks < 4; ++ks) {
    const int kb = ks * 32 + kgrp * 8;
    float4 ua = *reinterpret_cast<const float4*>(U + kb);
    float4 ub = *reinterpret_cast<const float4*>(U + kb + 4);
    float4 va = *reinterpret_cast<const float4*>(V0 + kb);
    float4 vb = *reinterpret_cast<const float4*>(V0 + kb + 4);
    short8v a0h, a0l;
    SPL8(a0h, a0l, 0, fmaxf(ua.x + va.x, 0.f));
    SPL8(a0h, a0l, 1, fmaxf(ua.y + va.y, 0.f));
    SPL8(a0h, a0l, 2, fmaxf(ua.z + va.z, 0.f));
    SPL8(a0h, a0l, 3, fmaxf(ua.w + va.w, 0.f));
    SPL8(a0h, a0l, 4, fmaxf(ub.x + vb.x, 0.f));
    SPL8(a0h, a0l, 5, fmaxf(ub.y + vb.y, 0.f));
    SPL8(a0h, a0l, 6, fmaxf(ub.z + vb.z, 0.f));
    SPL8(a0h, a0l, 7, fmaxf(ub.w + vb.w, 0.f));
    va = *reinterpret_cast<const float4*>(V1 + kb);
    vb = *reinterpret_cast<const float4*>(V1 + kb + 4);
    short8v a1h, a1l;
    SPL8(a1h, a1l, 0, fmaxf(ua.x + va.x, 0.f));
    SPL8(a1h, a1l, 1, fmaxf(ua.y + va.y, 0.f));
    SPL8(a1h, a1l, 2, fmaxf(ua.z + va.z, 0.f));
    SPL8(a1h, a1l, 3, fmaxf(ua.w + va.w, 0.f));
    SPL8(a1h, a1l, 4, fmaxf(ub.x + vb.x, 0.f));
    SPL8(a1h, a1l, 5, fmaxf(ub.y + vb.y, 0.f));
    SPL8(a1h, a1l, 6, fmaxf(ub.z + vb.z, 0.f));
    SPL8(a1h, a1l, 7, fmaxf(ub.w + vb.w, 0.f));
    #pragma unroll
    for (int tg = 0; tg < 8; ++tg) {
      const unsigned short* bp = wpk + ((size_t)(tg * 4 + ks) * 64 + l) * 16;
      short8v bh = *reinterpret_cast<const short8v*>(bp);
      short8v bl = *reinterpret_cast<const short8v*>(bp + 8);
      acc0[tg] = __builtin_amdgcn_mfma_f32_16x16x32_bf16(a0h, bh, acc0[tg], 0, 0, 0);
      acc0[tg] = __builtin_amdgcn_mfma_f32_16x16x32_bf16(a0h, bl, acc0[tg], 0, 0, 0);
      acc0[tg] = __builtin_amdgcn_mfma_f32_16x16x32_bf16(a0l, bh, acc0[tg], 0, 0, 0);
      acc1[tg] = __builtin_amdgcn_mfma_f32_16x16x32_bf16(a1h, bh, acc1[tg], 0, 0, 0);
      acc1[tg] = __builtin_amdgcn_mfma_f32_16x16x32_bf16(a1h, bl, acc1[tg], 0, 0, 0);
      acc1[tg] = __builtin_amdgcn_mfma_f32_16x16x32_bf16(a1l, bh, acc1[tg], 0, 0, 0);
    }
  }

  #pragma unroll
  for (int tg = 0; tg < 8; ++tg) {
    float m = fmaxf(fmaxf(acc0[tg][0], acc0[tg][1]),
                    fmaxf(acc0[tg][2], acc0[tg][3]));
    m = fmaxf(m, fmaxf(fmaxf(acc1[tg][0], acc1[tg][1]),
                       fmaxf(acc1[tg][2], acc1[tg][3])));
    m = fmaxf(m, __shfl_xor(m, 16));
    m = fmaxf(m, __shfl_xor(m, 32));
    if (kgrp == 0) {
      int n = tg * 16 + arow;
      Y[(size_t)pt * 128 + n] = m + b2[n];
    }
  }
}

// ------- fused fe: BOTH phases split-bf16 MFMA (R13/R15-proven) ------------
#define FRT 16
__global__ __launch_bounds__(256) void fe_fused_kernel(
    const float* __restrict__ x4, const unsigned short* __restrict__ wpf1,
    const float* __restrict__ b1, const unsigned short* __restrict__ wpack,
    const float* __restrict__ b2, float* __restrict__ part) {
  __shared__ unsigned short xh[FRT][136];
  __shared__ unsigned short xl[FRT][136];
  __shared__ unsigned short h1h[FRT][1032];
  __shared__ unsigned short h1l[FRT][1032];
  const int tile = blockIdx.x;
  const int r0 = tile * FRT;
  const int t = threadIdx.x;

  for (int e = t; e < FRT * 32; e += 256) {
    int r = e / 32, c4 = e % 32;
    float4 v = *reinterpret_cast<const float4*>(&x4[(size_t)(r0 + r) * 128 + c4 * 4]);
    unsigned short h0 = bf16hi(v.x), h1_ = bf16hi(v.y), h2 = bf16hi(v.z), h3 = bf16hi(v.w);
    xh[r][c4 * 4 + 0] = h0; xh[r][c4 * 4 + 1] = h1_;
    xh[r][c4 * 4 + 2] = h2; xh[r][c4 * 4 + 3] = h3;
    xl[r][c4 * 4 + 0] = bf16hi(v.x - bf16tof(h0));
    xl[r][c4 * 4 + 1] = bf16hi(v.y - bf16tof(h1_));
    xl[r][c4 * 4 + 2] = bf16hi(v.z - bf16tof(h2));
    xl[r][c4 * 4 + 3] = bf16hi(v.w - bf16tof(h3));
  }
  __syncthreads();

  const int l = t & 63;
  const int wv = t >> 6;
  const int arow = l & 15;
  const int kgrp = l >> 4;

  {
    short8v ahv[4], alv[4];
    #pragma unroll
    for (int ks = 0; ks < 4; ++ks) {
      ahv[ks] = *reinterpret_cast<const short8v*>(&xh[arow][ks * 32 + kgrp * 8]);
      alv[ks] = *reinterpret_cast<const short8v*>(&xl[arow][ks * 32 + kgrp * 8]);
    }
    #pragma unroll
    for (int tg = 0; tg < 16; ++tg) {
      const int tgg = wv * 16 + tg;
      f32x4v a1 = {0.f, 0.f, 0.f, 0.f};
      #pragma unroll
      for (int ks = 0; ks < 4; ++ks) {
        const unsigned short* bp = wpf1 + ((size_t)(tgg * 4 + ks) * 64 + l) * 16;
        short8v bh = *reinterpret_cast<const short8v*>(bp);
        short8v bl = *reinterpret_cast<const short8v*>(bp + 8);
        a1 = __builtin_amdgcn_mfma_f32_16x16x32_bf16(ahv[ks], bh, a1, 0, 0, 0);
        a1 = __builtin_amdgcn_mfma_f32_16x16x32_bf16(ahv[ks], bl, a1, 0, 0, 0);
        a1 = __builtin_amdgcn_mfma_f32_16x16x32_bf16(alv[ks], bh, a1, 0, 0, 0);
      }
      const int col = tgg * 16 + arow;
      const float bb = b1[col];
      #pragma unroll
      for (int i = 0; i < 4; ++i) {
        float v = fmaxf(a1[i] + bb, 0.f);
        unsigned short h = bf16hi(v);
        h1h[kgrp * 4 + i][col] = h;
        h1l[kgrp * 4 + i][col] = bf16hi(v - bf16tof(h));
      }
    }
  }
  __syncthreads();

  #pragma unroll
  for (int tc = 0; tc < 4; ++tc) {
    f32x4v accm[4];
    f32x4v zz = {0.f, 0.f, 0.f, 0.f};
    #pragma unroll
    for (int i = 0; i < 4; ++i) accm[i] = zz;

    const int tgb = wv * 16 + tc * 4;
    short8v bhC[4], blC[4], bhN[4], blN[4];
    #pragma unroll
    for (int tt = 0; tt < 4; ++tt) {
      const unsigned short* bp = wpack + ((size_t)((tgb + tt) * 32 + 0) * 64 + l) * 16;
      bhC[tt] = *reinterpret_cast<const short8v*>(bp);
      blC[tt] = *reinterpret_cast<const short8v*>(bp + 8);
    }
    for (int ks = 0; ks < 32; ++ks) {
      if (ks < 31) {
        #pragma unroll
        for (int tt = 0; tt < 4; ++tt) {
          const unsigned short* bp =
              wpack + ((size_t)((tgb + tt) * 32 + ks + 1) * 64 + l) * 16;
          bhN[tt] = *reinterpret_cast<const short8v*>(bp);
          blN[tt] = *reinterpret_cast<const short8v*>(bp + 8);
        }
      }
      const int kb = ks * 32 + kgrp * 8;
      short8v ah = *reinterpret_cast<const short8v*>(&h1h[arow][kb]);
      short8v al = *reinterpret_cast<const short8v*>(&h1l[arow][kb]);
      #pragma unroll
      for (int tt = 0; tt < 4; ++tt) {
        accm[tt] = __builtin_amdgcn_mfma_f32_16x16x32_bf16(ah, bhC[tt], accm[tt], 0, 0, 0);
        accm[tt] = __builtin_amdgcn_mfma_f32_16x16x32_bf16(ah, blC[tt], accm[tt], 0, 0, 0);
        accm[tt] = __builtin_amdgcn_mfma_f32_16x16x32_bf16(al, bhC[tt], accm[tt], 0, 0, 0);
      }
      #pragma unroll
      for (int tt = 0; tt < 4; ++tt) { bhC[tt] = bhN[tt]; blC[tt] = blN[tt]; }
    }
    #pragma unroll
    for (int tt = 0; tt < 4; ++tt) {
      float m = fmaxf(fmaxf(accm[tt][0], accm[tt][1]),
                      fmaxf(accm[tt][2], accm[tt][3]));
      m = fmaxf(m, __shfl_xor(m, 16));
      m = fmaxf(m, __shfl_xor(m, 32));
      if (kgrp == 0) {
        int n = (wv * 16 + tc * 4 + tt) * 16 + arow;
        part[(size_t)tile * 1024 + n] = m + b2[n];
      }
    }
  }
}

// --------------------------- reduce partials -> g ---------------------------
__global__ void reduce_g_kernel(const float* __restrict__ part, float* __restrict__ g) {
  int e = blockIdx.x * 256 + threadIdx.x;
  if (e >= kB * 1024) return;
  int b = e / 1024, c = e % 1024;
  const int tilesPerBatch = kN / FRT;  // 256
  const float* p = part + (size_t)b * tilesPerBatch * 1024 + c;
  float m = -INFINITY;
  for (int t = 0; t < tilesPerBatch; ++t) m = fmaxf(m, p[(size_t)t * 1024]);
  g[e] = m;
}

// --------------- per-batch head-0 g-contribution: gvec = g@W[326:]+b -------
__global__ void ghead_kernel(const float* __restrict__ g,
                             const float* __restrict__ h0W,
                             const float* __restrict__ h0b,
                             float* __restrict__ gvec) {
  const int b = blockIdx.x;
  const int n = threadIdx.x;
  float acc = h0b[n];
  const float* gb = g + (size_t)b * 1024;
  for (int k = 0; k < 1024; ++k)
    acc = fmaf(gb[k], h0W[(size_t)(326 + k) * 256 + n], acc);
  gvec[b * 256 + n] = acc;
}

// ---------- head MFMA GEMM: out = act(A@B + bias), A fp32 chunk-local ------
template <int KD, int NN>
__global__ __launch_bounds__(256) void head_mfma_kernel(
    const float* __restrict__ A, const unsigned short* __restrict__ bpk,
    const float* __restrict__ bias, float* __restrict__ out, int relu) {
  constexpr int NKS = KD / 32;
  __shared__ unsigned short ah[32][KD + 8];
  __shared__ unsigned short al[32][KD + 8];
  const int t = threadIdx.x;
  const int m0 = blockIdx.y * 32;
  const int n0 = blockIdx.x * 128;

  for (int e = t; e < 32 * (KD / 4); e += 256) {
    int r = e / (KD / 4), c4 = e % (KD / 4);
    float4 v = *reinterpret_cast<const float4*>(&A[(size_t)(m0 + r) * KD + c4 * 4]);
    unsigned short h0 = bf16hi(v.x), h1 = bf16hi(v.y), h2 = bf16hi(v.z), h3 = bf16hi(v.w);
    ah[r][c4 * 4 + 0] = h0; ah[r][c4 * 4 + 1] = h1;
    ah[r][c4 * 4 + 2] = h2; ah[r][c4 * 4 + 3] = h3;
    al[r][c4 * 4 + 0] = bf16hi(v.x - bf16tof(h0));
    al[r][c4 * 4 + 1] = bf16hi(v.y - bf16tof(h1));
    al[r][c4 * 4 + 2] = bf16hi(v.z - bf16tof(h2));
    al[r][c4 * 4 + 3] = bf16hi(v.w - bf16tof(h3));
  }
  __syncthreads();

  const int l = t & 63;
  const int wv = t >> 6;
  const int rf = wv >> 1;
  const int ch = wv & 1;
  const int arow = rf * 16 + (l & 15);
  const int kgrp = l >> 4;

  f32x4v acc[4];
  f32x4v zz = {0.f, 0.f, 0.f, 0.f};
  #pragma unroll
  for (int i = 0; i < 4; ++i) acc[i] = zz;

  for (int ks = 0; ks < NKS; ++ks) {
    const int kb = ks * 32 + kgrp * 8;
    short8v a_h = *reinterpret_cast<const short8v*>(&ah[arow][kb]);
    short8v a_l = *reinterpret_cast<const short8v*>(&al[arow][kb]);
    #pragma unroll
    for (int tg = 0; tg < 4; ++tg) {
      const int tgg = n0 / 16 + ch * 4 + tg;
      const unsigned short* bp = bpk + ((size_t)(tgg * NKS + ks) * 64 + l) * 16;
      short8v bh = *reinterpret_cast<const short8v*>(bp);
      short8v bl = *reinterpret_cast<const short8v*>(bp + 8);
      acc[tg] = __builtin_amdgcn_mfma_f32_16x16x32_bf16(a_h, bh, acc[tg], 0, 0, 0);
      acc[tg] = __builtin_amdgcn_mfma_f32_16x16x32_bf16(a_h, bl, acc[tg], 0, 0, 0);
      acc[tg] = __builtin_amdgcn_mfma_f32_16x16x32_bf16(a_l, bh, acc[tg], 0, 0, 0);
    }
  }

  #pragma unroll
  for (int tg = 0; tg < 4; ++tg) {
    int col = n0 + (ch * 4 + tg) * 16 + (l & 15);
    float bb = bias[col];
    #pragma unroll
    for (int i = 0; i < 4; ++i) {
      int row = m0 + rf * 16 + kgrp * 4 + i;
      float v = acc[tg][i] + bb;
      if (relu) v = fmaxf(v, 0.f);
      out[(size_t)row * NN + col] = v;
    }
  }
}

// ------------------------------- GEMM --------------------------------------
struct FeatSrc {
  const float* x0; const float* x1; const float* x2;
  const float* x3; const float* x4; const float* g;
};

template <int ASRC>
__device__ __forceinline__ float a_fetch(const float* __restrict__ A,
                                         const FeatSrc& fs, int row, int k, int Kd) {
  if constexpr (ASRC == 0) {
    return A[(size_t)row * Kd + k];
  } else {
    if (k < 6)        return fs.x0[(size_t)row * 8 + k];
    else if (k < 70)  return fs.x1[(size_t)row * 64 + (k - 6)];
    else if (k < 134) return fs.x2[(size_t)row * 64 + (k - 70)];
    else if (k < 198) return fs.x3[(size_t)row * 64 + (k - 134)];
    else              return fs.x4[(size_t)row * 128 + (k - 198)];
  }
}

// ---------- head-0 MFMA: gather-A (K=326 padded to 352), per-batch bias ----
__global__ __launch_bounds__(256) void head0_mfma_kernel(
    FeatSrc fs, const unsigned short* __restrict__ bpk,
    const float* __restrict__ gvec, float* __restrict__ out, int row0) {
  constexpr int KD = 352, NKS = 11, NN = 256;
  __shared__ unsigned short ah[32][KD + 8];
  __shared__ unsigned short al[32][KD + 8];
  const int t = threadIdx.x;
  const int m0 = blockIdx.y * 32;
  const int n0 = blockIdx.x * 128;

  for (int e = t; e < 32 * (KD / 4); e += 256) {
    int r = e / (KD / 4), c4 = e % (KD / 4);
    const int grow = row0 + m0 + r;
    #pragma unroll
    for (int j = 0; j < 4; ++j) {
      int k = c4 * 4 + j;
      float v = (k < 326) ? a_fetch<1>(nullptr, fs, grow, k, 0) : 0.f;
      unsigned short h = bf16hi(v);
      ah[r][k] = h;
      al[r][k] = bf16hi(v - bf16tof(h));
    }
  }
  __syncthreads();

  const int l = t & 63;
  const int wv = t >> 6;
  const int rf = wv >> 1;
  const int ch = wv & 1;
  const int arow = rf * 16 + (l & 15);
  const int kgrp = l >> 4;

  f32x4v acc[4];
  f32x4v zz = {0.f, 0.f, 0.f, 0.f};
  #pragma unroll
  for (int i = 0; i < 4; ++i) acc[i] = zz;

  for (int ks = 0; ks < NKS; ++ks) {
    const int kb = ks * 32 + kgrp * 8;
    short8v a_h = *reinterpret_cast<const short8v*>(&ah[arow][kb]);
    short8v a_l = *reinterpret_cast<const short8v*>(&al[arow][kb]);
    #pragma unroll
    for (int tg = 0; tg < 4; ++tg) {
      const int tgg = n0 / 16 + ch * 4 + tg;
      const unsigned short* bp = bpk + ((size_t)(tgg * NKS + ks) * 64 + l) * 16;
      short8v bh = *reinterpret_cast<const short8v*>(bp);
      short8v bl = *reinterpret_cast<const short8v*>(bp + 8);
      acc[tg] = __builtin_amdgcn_mfma_f32_16x16x32_bf16(a_h, bh, acc[tg], 0, 0, 0);
      acc[tg] = __builtin_amdgcn_mfma_f32_16x16x32_bf16(a_h, bl, acc[tg], 0, 0, 0);
      acc[tg] = __builtin_amdgcn_mfma_f32_16x16x32_bf16(a_l, bh, acc[tg], 0, 0, 0);
    }
  }

  const int bidx = (row0 + m0) >> 12;  // 32-row tile never crosses batch
  #pragma unroll
  for (int tg = 0; tg < 4; ++tg) {
    int col = n0 + (ch * 4 + tg) * 16 + (l & 15);
    float bb = gvec[(size_t)bidx * 256 + col];
    #pragma unroll
    for (int i = 0; i < 4; ++i) {
      int row = m0 + rf * 16 + kgrp * 4 + i;
      float v = fmaxf(acc[tg][i] + bb, 0.f);
      out[(size_t)row * NN + col] = v;
    }
  }
}

#define GBM 64
#define GBN 64
#define GBK 16

template <int ASRC>
__global__ __launch_bounds__(256) void gemm_kernel(
    const float* __restrict__ A, FeatSrc fs,
    const float* __restrict__ Bm, const float* __restrict__ bias,
    float* __restrict__ out, int row0, int Nn, int Kd, int relu, int biasb) {
  __shared__ float As[GBK][GBM + 4];
  __shared__ float Bs[GBK][GBN];

  const int tid = threadIdx.x;
  const int tx = tid % 16, ty = tid / 16;
  const int m0 = blockIdx.y * GBM;
  const int n0 = blockIdx.x * GBN;

  float acc[4][4] = {};

  for (int k0 = 0; k0 < Kd; k0 += GBK) {
    #pragma unroll
    for (int r = 0; r < 4; ++r) {
      int ee = tid + r * 256;
      int ar = ee / GBK, ak = ee % GBK;
      int kk = k0 + ak;
      float v = 0.f;
      if (kk < Kd) {
        int arow = (ASRC == 1) ? (row0 + m0 + ar) : (m0 + ar);
        v = a_fetch<ASRC>(A, fs, arow, kk, Kd);
      }
      As[ak][ar] = v;
    }
    #pragma unroll
    for (int r = 0; r < 4; ++r) {
      int ee = tid + r * 256;
      int bk = ee / GBN, bn = ee % GBN;
      int kk = k0 + bk;
      float v = 0.f;
      if (kk < Kd && (n0 + bn) < Nn) v = Bm[(size_t)kk * Nn + n0 + bn];
      Bs[bk][bn] = v;
    }
    __syncthreads();
    #pragma unroll
    for (int kk = 0; kk < GBK; ++kk) {
      float4 a4 = *reinterpret_cast<const float4*>(&As[kk][ty * 4]);
      float4 b4 = *reinterpret_cast<const float4*>(&Bs[kk][tx * 4]);
      float av[4] = {a4.x, a4.y, a4.z, a4.w};
      float bv[4] = {b4.x, b4.y, b4.z, b4.w};
      #pragma unroll
      for (int i2 = 0; i2 < 4; ++i2)
        #pragma unroll
        for (int j2 = 0; j2 < 4; ++j2)
          acc[i2][j2] = fmaf(av[i2], bv[j2], acc[i2][j2]);
    }
    __syncthreads();
  }

  #pragma unroll
  for (int j2 = 0; j2 < 4; ++j2) {
    int n = n0 + tx * 4 + j2;
    if (n >= Nn) continue;
    #pragma unroll
    for (int i2 = 0; i2 < 4; ++i2) {
      float bb;
      if (biasb) {
        int grow = row0 + m0 + ty * 4 + i2;
        bb = bias[(size_t)(grow >> 12) * 256 + n];
      } else {
        bb = bias ? bias[n] : 0.f;
      }
      float v = acc[i2][j2] + bb;
      if (relu) v = fmaxf(v, 0.f);
      out[(size_t)(m0 + ty * 4 + i2) * Nn + n] = v;
    }
  }
}

// --------- fused h3 (128->13) + log_softmax: one wave per row --------------
__global__ __launch_bounds__(256) void fused_logits_kernel(
    const float* __restrict__ h128, const float* __restrict__ W,
    const float* __restrict__ b, float* __restrict__ out, int row0) {
  __shared__ float sm[4][128];
  const int t = threadIdx.x;
  const int w = t >> 6;
  const int l = t & 63;
  const int row = blockIdx.x * 4 + w;

  sm[w][l] = h128[(size_t)row * 128 + l];
  sm[w][64 + l] = h128[(size_t)row * 128 + 64 + l];
  __syncthreads();

  float v = 0.f;
  if (l < 13) {
    for (int k = 0; k < 128; ++k) v = fmaf(sm[w][k], W[(size_t)k * 13 + l], v);
    v += b[l];
  }
  float mv = (l < 13) ? v : -INFINITY;
  #pragma unroll
  for (int off = 8; off > 0; off >>= 1) mv = fmaxf(mv, __shfl_xor(mv, off));
  float ev = (l < 13) ? expf(v - mv) : 0.f;
  float sv = ev;
  #pragma unroll
  for (int off = 8; off > 0; off >>= 1) sv += __shfl_xor(sv, off);
  if (l < 13) {
    out[(size_t)(row0 + row) * 13 + l] = v - mv - logf(sv);
  }
}

// ------------------------------- launch ------------------------------------
static void run_knn(const float* X, const float* nrm, float* Dbuf, int* nidx,
                    int CS, int dq, hipStream_t stream) {
  for (int b = 0; b < kB; ++b) {
    for (int h = 0; h < kN / dq; ++h) {
      dim3 g(kN / 64, dq / 64);
      if (CS == 8)
        dist_gemm_kernel<8><<<g, 256, 0, stream>>>(
            X + (size_t)b * kN * 8, nrm + (size_t)b * kN, Dbuf, h * dq);
      else
        dist_gemm_kernel<64><<<g, 256, 0, stream>>>(
            X + (size_t)b * kN * 64, nrm + (size_t)b * kN, Dbuf, h * dq);
      knn_select_kernel<<<dq / 4, 256, 0, stream>>>(Dbuf, nidx,
                                                    b * kN + h * dq);
    }
  }
}

extern "C" void kernel_launch(void* const* d_in, const int* in_sizes, int n_in,
                              void* d_out, int out_size, void* d_ws, size_t ws_size,
                              hipStream_t stream) {
  const float* x    = (const float*)d_in[0];
  const float* pos  = (const float*)d_in[1];
  const float* e1W1 = (const float*)d_in[2];
  const float* e1b1 = (const float*)d_in[3];
  const float* e1W2 = (const float*)d_in[4];
  const float* e1b2 = (const float*)d_in[5];
  const float* e2W1 = (const float*)d_in[6];
  const float* e2b1 = (const float*)d_in[7];
  const float* e2W2 = (const float*)d_in[8];
  const float* e2b2 = (const float*)d_in[9];
  const float* e3W1 = (const float*)d_in[10];
  const float* e3b1 = (const float*)d_in[11];
  const float* e3W2 = (const float*)d_in[12];
  const float* e3b2 = (const float*)d_in[13];
  const float* e4W1 = (const float*)d_in[14];
  const float* e4b1 = (const float*)d_in[15];
  const float* e4W2 = (const float*)d_in[16];
  const float* e4b2 = (const float*)d_in[17];
  const float* feW1 = (const float*)d_in[18];
  const float* feb1 = (const float*)d_in[19];
  const float* feW2 = (const float*)d_in[20];
  const float* feb2 = (const float*)d_in[21];
  const float* h0W  = (const float*)d_in[22];
  const float* h0b  = (const float*)d_in[23];
  const float* h1W  = (const float*)d_in[24];
  const float* h1b  = (const float*)d_in[25];
  const float* h2W  = (const float*)d_in[26];
  const float* h2b  = (const float*)d_in[27];
  const float* h3W  = (const float*)d_in[28];
  const float* h3b  = (const float*)d_in[29];

  float* W = (float*)d_ws;
  size_t off = 0;
  float* x0p  = W + off; off += (size_t)kBN * 8;
  float* x1   = W + off; off += (size_t)kBN * 64;
  float* x2   = W + off; off += (size_t)kBN * 64;
  float* x3   = W + off; off += (size_t)kBN * 64;
  float* x4   = W + off; off += (size_t)kBN * 128;
  float* gmax = W + off; off += (size_t)kB * 1024;
  float* gvec = W + off; off += (size_t)kB * 256;
  float* nrm  = W + off; off += (size_t)kBN;
  int*   nidx = (int*)(W + off); off += (size_t)kBN * kK;
  float* wu   = W + off; off += (size_t)64 * 256;
  float* b1e  = W + off; off += 256;
  unsigned short* wpack = (unsigned short*)(W + off); off += (size_t)1048576; // 4MB
  unsigned short* wpk4  = (unsigned short*)(W + off); off += (size_t)16384;   // 64KB
  unsigned short* wph1  = (unsigned short*)(W + off); off += (size_t)65536;   // 256KB
  unsigned short* wph2  = (unsigned short*)(W + off); off += (size_t)32768;   // 128KB
  unsigned short* wpf1  = (unsigned short*)(W + off); off += (size_t)131072;  // 512KB
  unsigned short* wph0  = (unsigned short*)(W + off); off += (size_t)90112;   // 352KB (16*11*64*16 ushorts)
  // transient union: D chunk / uv (33.5MB) / fe part / head bufs
  float* trans = W + off;
  float* Dbuf = trans;
  float* uv   = trans;
  float* part = trans;
  float* ping = trans;
  float* pong = ping + (size_t)kCH * 256;
  float* h128 = pong + (size_t)kCH * 256;

  // runtime-gated kNN D-chunk: 4096 rows (64MB) if workspace allows
  const size_t need4096 = (off + (size_t)4096 * kN) * 4;
  const int dq = (ws_size >= need4096) ? 4096 : 2048;

  FeatSrc fs{x0p, x1, x2, x3, x4, gmax};

  concat_x0_kernel<<<(kBN * 8 + 255) / 256, 256, 0, stream>>>(x, pos, x0p);

  // ---- edge conv 1: C=6 (CS=8), H1=64, H2=64 ----
  norms_kernel<6, 8><<<(kBN + 255) / 256, 256, 0, stream>>>(x0p, nrm);
  run_knn(x0p, nrm, Dbuf, nidx, 8, dq, stream);
  prep_uv_kernel<<<(8 * 128 + 255) / 256, 256, 0, stream>>>(e1W1, e1b1, wu, b1e, 6, 64, 8);
  gemm_kernel<0><<<dim3(128 / GBN, kBN / GBM), 256, 0, stream>>>(
      x0p, fs, wu, b1e, uv, 0, 128, 8, 0, 0);
  gather_gemm2_max_kernel<64><<<dim3(1, kBN / 2), 256, 0, stream>>>(
      uv, nidx, e1W2, e1b2, x1, 64);

  // ---- edge conv 2: C=64, H1=64, H2=64 ----
  norms_kernel<64, 64><<<(kBN + 255) / 256, 256, 0, stream>>>(x1, nrm);
  run_knn(x1, nrm, Dbuf, nidx, 64, dq, stream);
  prep_uv_kernel<<<(64 * 128 + 255) / 256, 256, 0, stream>>>(e2W1, e2b1, wu, b1e, 64, 64, 64);
  gemm_kernel<0><<<dim3(128 / GBN, kBN / GBM), 256, 0, stream>>>(
      x1, fs, wu, b1e, uv, 0, 128, 64, 0, 0);
  gather_gemm2_max_kernel<64><<<dim3(1, kBN / 2), 256, 0, stream>>>(
      uv, nidx, e2W2, e2b2, x2, 64);

  // ---- edge conv 3 ----
  norms_kernel<64, 64><<<(kBN + 255) / 256, 256, 0, stream>>>(x2, nrm);
  run_knn(x2, nrm, Dbuf, nidx, 64, dq, stream);
  prep_uv_kernel<<<(64 * 128 + 255) / 256, 256, 0, stream>>>(e3W1, e3b1, wu, b1e, 64, 64, 64);
  gemm_kernel<0><<<dim3(128 / GBN, kBN / GBM), 256, 0, stream>>>(
      x2, fs, wu, b1e, uv, 0, 128, 64, 0, 0);
  gather_gemm2_max_kernel<64><<<dim3(1, kBN / 2), 256, 0, stream>>>(
      uv, nidx, e3W2, e3b2, x3, 64);

  // ---- edge conv 4: C=64, H1=128, H2=128 (MFMA gather) ----
  norms_kernel<64, 64><<<(kBN + 255) / 256, 256, 0, stream>>>(x3, nrm);
  run_knn(x3, nrm, Dbuf, nidx, 64, dq, stream);
  prep_uv_kernel<<<(64 * 256 + 255) / 256, 256, 0, stream>>>(e4W1, e4b1, wu, b1e, 64, 128, 64);
  gemm_kernel<0><<<dim3(256 / GBN, kBN / GBM), 256, 0, stream>>>(
      x3, fs, wu, b1e, uv, 0, 256, 64, 0, 0);
  pack_w2gen_kernel<<<64, 256, 0, stream>>>(e4W2, wpk4, 128, 128);
  gather_mfma_max_kernel<<<kBN / 4, 256, 0, stream>>>(uv, nidx, wpk4, e4b2, x4);

  // ---- fe fused (both phases MFMA) + global max + ghead ----
  pack_w2_kernel<<<4096, 256, 0, stream>>>(feW2, wpack);
  pack_w2gen_kernel<<<512, 256, 0, stream>>>(feW1, wpf1, 128, 1024);
  fe_fused_kernel<<<kBN / FRT, 256, 0, stream>>>(x4, wpf1, feb1, wpack, feb2, part);
  reduce_g_kernel<<<(kB * 1024 + 255) / 256, 256, 0, stream>>>(part, gmax);
  ghead_kernel<<<kB, 256, 0, stream>>>(gmax, h0W, h0b, gvec);

  // ---- pack head weights for MFMA ----
  pack_h0_kernel<<<(16 * 11 * 512 + 255) / 256, 256, 0, stream>>>(h0W, wph0);
  pack_w2gen_kernel<<<(16 * 8 * 512 + 255) / 256, 256, 0, stream>>>(h1W, wph1, 256, 256);
  pack_w2gen_kernel<<<(8 * 8 * 512 + 255) / 256, 256, 0, stream>>>(h2W, wph2, 256, 128);

  // ---- head, chunked over rows ----
  for (int c = 0; c < kBN / kCH; ++c) {
    int row0 = c * kCH;
    head0_mfma_kernel<<<dim3(2, kCH / 32), 256, 0, stream>>>(
        fs, wph0, gvec, ping, row0);
    head_mfma_kernel<256, 256><<<dim3(2, kCH / 32), 256, 0, stream>>>(
        ping, wph1, h1b, pong, 1);
    head_mfma_kernel<256, 128><<<dim3(1, kCH / 32), 256, 0, stream>>>(
        pong, wph2, h2b, h128, 1);
    fused_logits_kernel<<<kCH / 4, 256, 0, stream>>>(
        h128, h3W, h3b, (float*)d_out, row0);
  }
}

// Round 18
// 3828.226 us; speedup vs baseline: 1.4293x; 1.0158x over previous
//
#include <hip/hip_runtime.h>
#include <math.h>

#define kB 8
#define kN 4096
#define kBN (kB * kN)
#define kK 30

typedef __attribute__((ext_vector_type(8))) short short8v;
typedef __attribute__((ext_vector_type(4))) float f32x4v;

__device__ __forceinline__ unsigned short bf16hi(float a) {
  union { float f; unsigned u; } v; v.f = a;
  unsigned r = v.u + 0x7FFF + ((v.u >> 16) & 1);
  return (unsigned short)(r >> 16);
}
__device__ __forceinline__ float bf16tof(unsigned short h) {
  union { float f; unsigned u; } v; v.u = ((unsigned)h) << 16;
  return v.f;
}

// ----------------------------- concat x0 (padded to 8 ch) -----------------
__global__ void concat_x0_kernel(const float* __restrict__ x,
                                 const float* __restrict__ pos,
                                 float* __restrict__ x0p) {
  int e = blockIdx.x * 256 + threadIdx.x;
  if (e >= kBN * 8) return;
  int p = e / 8, c = e % 8;
  float v = 0.f;
  if (c < 3) v = x[(size_t)p * 3 + c];
  else if (c < 6) v = pos[(size_t)p * 3 + (c - 3)];
  x0p[e] = v;
}

// ------------------------------ norms ------------------------------------
template <int C, int CS>
__global__ void norms_kernel(const float* __restrict__ X, float* __restrict__ nrm) {
  int p = blockIdx.x * 256 + threadIdx.x;
  if (p >= kBN) return;
  const float* xp = X + (size_t)p * CS;
  float s = 0.f;
  for (int c = 0; c < C; ++c) s = fmaf(xp[c], xp[c], s);
  nrm[p] = s;
}

// --------------------------- kNN: distance GEMM ----------------------------
template <int CS>
__global__ __launch_bounds__(256) void dist_gemm_kernel(
    const float* __restrict__ X, const float* __restrict__ nrm,
    float* __restrict__ D, int i0) {
  __shared__ float As[CS][64 + 4];
  __shared__ float Bs[CS][64 + 4];
  const int tid = threadIdx.x;
  const int tx = tid & 15, ty = tid >> 4;
  const int rI = i0 + blockIdx.y * 64;
  const int cJ = blockIdx.x * 64;

  constexpr int QUADS = CS / 4;
  for (int e = tid; e < 64 * QUADS; e += 256) {
    int r = e & 63, q = e >> 6;
    float4 v = *reinterpret_cast<const float4*>(X + (size_t)(rI + r) * CS + q * 4);
    As[q * 4 + 0][r] = v.x; As[q * 4 + 1][r] = v.y;
    As[q * 4 + 2][r] = v.z; As[q * 4 + 3][r] = v.w;
  }
  for (int e = tid; e < 64 * QUADS; e += 256) {
    int r = e & 63, q = e >> 6;
    float4 v = *reinterpret_cast<const float4*>(X + (size_t)(cJ + r) * CS + q * 4);
    Bs[q * 4 + 0][r] = v.x; Bs[q * 4 + 1][r] = v.y;
    Bs[q * 4 + 2][r] = v.z; Bs[q * 4 + 3][r] = v.w;
  }
  __syncthreads();

  float acc[4][4] = {};
  #pragma unroll
  for (int k = 0; k < CS; ++k) {
    float4 a4 = *reinterpret_cast<const float4*>(&As[k][ty * 4]);
    float4 b4 = *reinterpret_cast<const float4*>(&Bs[k][tx * 4]);
    float av[4] = {a4.x, a4.y, a4.z, a4.w};
    float bv[4] = {b4.x, b4.y, b4.z, b4.w};
    #pragma unroll
    for (int i2 = 0; i2 < 4; ++i2)
      #pragma unroll
      for (int j2 = 0; j2 < 4; ++j2)
        acc[i2][j2] = fmaf(av[i2], bv[j2], acc[i2][j2]);
  }

  float ni[4], nj[4];
  #pragma unroll
  for (int i2 = 0; i2 < 4; ++i2) ni[i2] = nrm[rI + ty * 4 + i2];
  #pragma unroll
  for (int j2 = 0; j2 < 4; ++j2) nj[j2] = nrm[cJ + tx * 4 + j2];

  #pragma unroll
  for (int i2 = 0; i2 < 4; ++i2) {
    float4 o;
    o.x = fmaf(2.f, acc[i2][0], -ni[i2]) - nj[0];
    o.y = fmaf(2.f, acc[i2][1], -ni[i2]) - nj[1];
    o.z = fmaf(2.f, acc[i2][2], -ni[i2]) - nj[2];
    o.w = fmaf(2.f, acc[i2][3], -ni[i2]) - nj[3];
    *reinterpret_cast<float4*>(
        &D[(size_t)(blockIdx.y * 64 + ty * 4 + i2) * kN + cJ + tx * 4]) = o;
  }
}

// --------------------------- kNN: selection --------------------------------
__global__ __launch_bounds__(256) void knn_select_kernel(
    const float* __restrict__ D, int* __restrict__ idx_out, int qbase) {
  const int w = threadIdx.x >> 6;
  const int l = threadIdx.x & 63;
  const int q = blockIdx.x * 4 + w;
  const float* __restrict__ row = D + (size_t)q * kN;

  float d[64];
  #pragma unroll
  for (int m = 0; m < 64; ++m) d[m] = row[m * 64 + l];

  float gv[4];
  int gm[4];
  #pragma unroll
  for (int g = 0; g < 4; ++g) {
    float bv = -INFINITY;
    int bm = g * 16;
    #pragma unroll
    for (int mm = 0; mm < 16; ++mm) {
      const int m = g * 16 + mm;
      if (d[m] > bv) { bv = d[m]; bm = m; }
    }
    gv[g] = bv;
    gm[g] = bm;
  }

  int myout = 0;
  for (int k = 0; k < kK; ++k) {
    float cv = gv[0];
    int cm = gm[0];
    if (gv[1] > cv) { cv = gv[1]; cm = gm[1]; }
    if (gv[2] > cv) { cv = gv[2]; cm = gm[2]; }
    if (gv[3] > cv) { cv = gv[3]; cm = gm[3]; }
    int cj = cm * 64 + l;
    #pragma unroll
    for (int off = 32; off > 0; off >>= 1) {
      float ov = __shfl_xor(cv, off);
      int oj = __shfl_xor(cj, off);
      if (ov > cv || (ov == cv && oj < cj)) { cv = ov; cj = oj; }
    }
    if (l == k) myout = cj;
    if ((cj & 63) == l) {
      const int om = cj >> 6;
      const int g = om >> 4;
#define RESCAN_GROUP(G)                                                  \
  {                                                                      \
    float nv = -INFINITY;                                                \
    int nm = (G) * 16;                                                   \
    _Pragma("unroll") for (int mm = 0; mm < 16; ++mm) {                  \
      const int m = (G) * 16 + mm;                                       \
      float dd = (m == om) ? -INFINITY : d[m];                           \
      d[m] = dd;                                                         \
      if (dd > nv) { nv = dd; nm = m; }                                  \
    }                                                                    \
    gv[G] = nv;                                                          \
    gm[G] = nm;                                                          \
  }
      if (g == 0) RESCAN_GROUP(0)
      else if (g == 1) RESCAN_GROUP(1)
      else if (g == 2) RESCAN_GROUP(2)
      else RESCAN_GROUP(3)
#undef RESCAN_GROUP
    }
  }
  if (l < kK) idx_out[(size_t)(qbase + q) * kK + l] = myout;
}

// -------------------- EdgeConv via U/V decomposition -----------------------
__global__ void prep_uv_kernel(const float* __restrict__ W1,
                               const float* __restrict__ b1,
                               float* __restrict__ wu, float* __restrict__ b1e,
                               int C, int H1, int CS) {
  const int n2 = 2 * H1;
  int e = blockIdx.x * 256 + threadIdx.x;
  if (e < n2) b1e[e] = (e < H1) ? b1[e] : 0.f;
  if (e >= CS * n2) return;
  int c = e / n2, n = e % n2;
  float v;
  if (c >= C) v = 0.f;
  else if (n < H1) v = W1[(size_t)c * H1 + n] - W1[(size_t)(C + c) * H1 + n];
  else v = W1[(size_t)(C + c) * H1 + (n - H1)];
  wu[e] = v;
}

// gather + GEMM2 + max (fp32, 2 points x 32 edges, K-chunk 32) — e1-e3
template <int H1>
__global__ __launch_bounds__(256) void gather_gemm2_max_kernel(
    const float* __restrict__ UV, const int* __restrict__ nidx,
    const float* __restrict__ W2, const float* __restrict__ b2,
    float* __restrict__ Y, int H2) {
  __shared__ float As[32][64 + 4];
  __shared__ float Ws[32][64];
  __shared__ float red[16][64];

  const int tid = threadIdx.x;
  const int tx = tid & 15, ty = tid >> 4;
  const int p0 = blockIdx.y * 2;
  const int n0 = blockIdx.x * 64;
  const int N2 = 2 * H1;

  const int r = tid >> 2;
  const int k4g = (tid & 3) * 4;
  const int pt = p0 + (r >> 5);
  int e = r & 31;
  if (e >= kK) e = 0;
  const int j = nidx[(size_t)pt * kK + e];
  const int jglob = (pt & ~(kN - 1)) + j;
  const float* __restrict__ Urow = UV + (size_t)pt * N2;
  const float* __restrict__ Vrow = UV + (size_t)jglob * N2 + H1;

  const int wk = tid >> 6;
  const int wn = tid & 63;

  float acc[4][4] = {};

  #pragma unroll
  for (int k0 = 0; k0 < H1; k0 += 32) {
    #pragma unroll
    for (int kq = 0; kq < 2; ++kq) {
      const int kk4 = k4g + kq * 16;
      float4 u4 = *reinterpret_cast<const float4*>(Urow + k0 + kk4);
      float4 v4 = *reinterpret_cast<const float4*>(Vrow + k0 + kk4);
      As[kk4 + 0][r] = fmaxf(u4.x + v4.x, 0.f);
      As[kk4 + 1][r] = fmaxf(u4.y + v4.y, 0.f);
      As[kk4 + 2][r] = fmaxf(u4.z + v4.z, 0.f);
      As[kk4 + 3][r] = fmaxf(u4.w + v4.w, 0.f);
    }
    #pragma unroll
    for (int qq = 0; qq < 8; ++qq)
      Ws[wk + qq * 4][wn] = W2[(size_t)(k0 + wk + qq * 4) * H2 + n0 + wn];
    __syncthreads();
    #pragma unroll
    for (int kk = 0; kk < 32; ++kk) {
      float4 a4 = *reinterpret_cast<const float4*>(&As[kk][ty * 4]);
      float4 b4 = *reinterpret_cast<const float4*>(&Ws[kk][tx * 4]);
      float av[4] = {a4.x, a4.y, a4.z, a4.w};
      float bv[4] = {b4.x, b4.y, b4.z, b4.w};
      #pragma unroll
      for (int i2 = 0; i2 < 4; ++i2)
        #pragma unroll
        for (int j2 = 0; j2 < 4; ++j2)
          acc[i2][j2] = fmaf(av[i2], bv[j2], acc[i2][j2]);
    }
    __syncthreads();
  }

  #pragma unroll
  for (int j2 = 0; j2 < 4; ++j2) {
    float m = fmaxf(fmaxf(acc[0][j2], acc[1][j2]), fmaxf(acc[2][j2], acc[3][j2]));
    red[ty][tx * 4 + j2] = m;
  }
  __syncthreads();
  if (tid < 128) {
    int ptl = tid >> 6, c = tid & 63;
    float m = red[ptl * 8][c];
    #pragma unroll
    for (int qq = 1; qq < 8; ++qq) m = fmaxf(m, red[ptl * 8 + qq][c]);
    Y[(size_t)(p0 + ptl) * H2 + n0 + c] = m + b2[n0 + c];
  }
}

// ---------------- pack feW2 (1024x1024) into MFMA fragment order -----------
__global__ void pack_w2_kernel(const float* __restrict__ W2,
                               unsigned short* __restrict__ wp) {
  int e = blockIdx.x * 256 + threadIdx.x;
  if (e >= 64 * 32 * 64 * 8) return;
  int i = e & 7;
  int lane = (e >> 3) & 63;
  int ks = (e >> 9) & 31;
  int tg = e >> 14;
  int n = tg * 16 + (lane & 15);
  int k = ks * 32 + (lane >> 4) * 8 + i;
  float w = W2[(size_t)k * 1024 + n];
  unsigned short hi = bf16hi(w);
  unsigned short lo = bf16hi(w - bf16tof(hi));
  size_t base = ((size_t)(tg * 32 + ks) * 64 + lane) * 16;
  wp[base + i] = hi;
  wp[base + 8 + i] = lo;
}

// ---------------- generic pack (K x N) into MFMA fragment order ------------
__global__ void pack_w2gen_kernel(const float* __restrict__ W2,
                                  unsigned short* __restrict__ wp,
                                  int H1, int H2) {
  int e = blockIdx.x * 256 + threadIdx.x;
  int nks = H1 / 32;
  int total = (H2 / 16) * nks * 64 * 8;
  if (e >= total) return;
  int i = e & 7;
  int lane = (e >> 3) & 63;
  int rem = e >> 9;
  int ks = rem % nks;
  int tg = rem / nks;
  int n = tg * 16 + (lane & 15);
  int k = ks * 32 + (lane >> 4) * 8 + i;
  float w = W2[(size_t)k * H2 + n];
  unsigned short hi = bf16hi(w);
  unsigned short lo = bf16hi(w - bf16tof(hi));
  size_t base = ((size_t)(tg * nks + ks) * 64 + lane) * 16;
  wp[base + i] = hi;
  wp[base + 8 + i] = lo;
}

// ---------------- pack h0W rows 0..325 (zero-pad to K=352), N=256 ----------
__global__ void pack_h0_kernel(const float* __restrict__ W,
                               unsigned short* __restrict__ wp) {
  int e = blockIdx.x * 256 + threadIdx.x;
  const int nks = 11;  // 352/32
  int total = 16 * nks * 64 * 8;
  if (e >= total) return;
  int i = e & 7;
  int lane = (e >> 3) & 63;
  int rem = e >> 9;
  int ks = rem % nks;
  int tg = rem / nks;
  int n = tg * 16 + (lane & 15);
  int k = ks * 32 + (lane >> 4) * 8 + i;
  float w = (k < 326) ? W[(size_t)k * 256 + n] : 0.f;
  unsigned short hi = bf16hi(w);
  unsigned short lo = bf16hi(w - bf16tof(hi));
  size_t base = ((size_t)(tg * nks + ks) * 64 + lane) * 16;
  wp[base + i] = hi;
  wp[base + 8 + i] = lo;
}

// -------- e4 gather + split-bf16 MFMA + max (H1=128, H2=128) ---------------
#define SPL8(h, l, i, val)                                        \
  { float _v = (val); unsigned short _h = bf16hi(_v);             \
    h[i] = (short)_h; l[i] = (short)bf16hi(_v - bf16tof(_h)); }

__global__ __launch_bounds__(256) void gather_mfma_max_kernel(
    const float* __restrict__ UV, const int* __restrict__ nidx,
    const unsigned short* __restrict__ wpk, const float* __restrict__ b2,
    float* __restrict__ Y) {
  const int t = threadIdx.x;
  const int l = t & 63;
  const int wv = t >> 6;
  const int pt = blockIdx.x * 4 + wv;
  const int arow = l & 15;
  const int kgrp = l >> 4;

  const int base = pt & ~(kN - 1);
  int e1 = 16 + arow;
  if (e1 >= kK) e1 = 0;
  const int j0 = base + nidx[(size_t)pt * kK + arow];
  const int j1 = base + nidx[(size_t)pt * kK + e1];
  const float* __restrict__ U  = UV + (size_t)pt * 256;
  const float* __restrict__ V0 = UV + (size_t)j0 * 256 + 128;
  const float* __restrict__ V1 = UV + (size_t)j1 * 256 + 128;

  f32x4v acc0[8], acc1[8];
  f32x4v zz = {0.f, 0.f, 0.f, 0.f};
  #pragma unroll
  for (int i = 0; i < 8; ++i) { acc0[i] = zz; acc1[i] = zz; }

  #pragma unroll
  for (int ks = 0; ks < 4; ++ks) {
    const int kb = ks * 32 + kgrp * 8;
    float4 ua = *reinterpret_cast<const float4*>(U + kb);
    float4 ub = *reinterpret_cast<const float4*>(U + kb + 4);
    float4 va = *reinterpret_cast<const float4*>(V0 + kb);
    float4 vb = *reinterpret_cast<const float4*>(V0 + kb + 4);
    short8v a0h, a0l;
    SPL8(a0h, a0l, 0, fmaxf(ua.x + va.x, 0.f));
    SPL8(a0h, a0l, 1, fmaxf(ua.y + va.y, 0.f));
    SPL8(a0h, a0l, 2, fmaxf(ua.z + va.z, 0.f));
    SPL8(a0h, a0l, 3, fmaxf(ua.w + va.w, 0.f));
    SPL8(a0h, a0l, 4, fmaxf(ub.x + vb.x, 0.f));
    SPL8(a0h, a0l, 5, fmaxf(ub.y + vb.y, 0.f));
    SPL8(a0h, a0l, 6, fmaxf(ub.z + vb.z, 0.f));
    SPL8(a0h, a0l, 7, fmaxf(ub.w + vb.w, 0.f));
    va = *reinterpret_cast<const float4*>(V1 + kb);
    vb = *reinterpret_cast<const float4*>(V1 + kb + 4);
    short8v a1h, a1l;
    SPL8(a1h, a1l, 0, fmaxf(ua.x + va.x, 0.f));
    SPL8(a1h, a1l, 1, fmaxf(ua.y + va.y, 0.f));
    SPL8(a1h, a1l, 2, fmaxf(ua.z + va.z, 0.f));
    SPL8(a1h, a1l, 3, fmaxf(ua.w + va.w, 0.f));
    SPL8(a1h, a1l, 4, fmaxf(ub.x + vb.x, 0.f));
    SPL8(a1h, a1l, 5, fmaxf(ub.y + vb.y, 0.f));
    SPL8(a1h, a1l, 6, fmaxf(ub.z + vb.z, 0.f));
    SPL8(a1h, a1l, 7, fmaxf(ub.w + vb.w, 0.f));
    #pragma unroll
    for (int tg = 0; tg < 8; ++tg) {
      const unsigned short* bp = wpk + ((size_t)(tg * 4 + ks) * 64 + l) * 16;
      short8v bh = *reinterpret_cast<const short8v*>(bp);
      short8v bl = *reinterpret_cast<const short8v*>(bp + 8);
      acc0[tg] = __builtin_amdgcn_mfma_f32_16x16x32_bf16(a0h, bh, acc0[tg], 0, 0, 0);
      acc0[tg] = __builtin_amdgcn_mfma_f32_16x16x32_bf16(a0h, bl, acc0[tg], 0, 0, 0);
      acc0[tg] = __builtin_amdgcn_mfma_f32_16x16x32_bf16(a0l, bh, acc0[tg], 0, 0, 0);
      acc1[tg] = __builtin_amdgcn_mfma_f32_16x16x32_bf16(a1h, bh, acc1[tg], 0, 0, 0);
      acc1[tg] = __builtin_amdgcn_mfma_f32_16x16x32_bf16(a1h, bl, acc1[tg], 0, 0, 0);
      acc1[tg] = __builtin_amdgcn_mfma_f32_16x16x32_bf16(a1l, bh, acc1[tg], 0, 0, 0);
    }
  }

  #pragma unroll
  for (int tg = 0; tg < 8; ++tg) {
    float m = fmaxf(fmaxf(acc0[tg][0], acc0[tg][1]),
                    fmaxf(acc0[tg][2], acc0[tg][3]));
    m = fmaxf(m, fmaxf(fmaxf(acc1[tg][0], acc1[tg][1]),
                       fmaxf(acc1[tg][2], acc1[tg][3])));
    m = fmaxf(m, __shfl_xor(m, 16));
    m = fmaxf(m, __shfl_xor(m, 32));
    if (kgrp == 0) {
      int n = tg * 16 + arow;
      Y[(size_t)pt * 128 + n] = m + b2[n];
    }
  }
}

// ------- fused fe: BOTH phases split-bf16 MFMA (R13/R15/R17-proven) --------
#define FRT 16
__global__ __launch_bounds__(256) void fe_fused_kernel(
    const float* __restrict__ x4, const unsigned short* __restrict__ wpf1,
    const float* __restrict__ b1, const unsigned short* __restrict__ wpack,
    const float* __restrict__ b2, float* __restrict__ part) {
  __shared__ unsigned short xh[FRT][136];
  __shared__ unsigned short xl[FRT][136];
  __shared__ unsigned short h1h[FRT][1032];
  __shared__ unsigned short h1l[FRT][1032];
  const int tile = blockIdx.x;
  const int r0 = tile * FRT;
  const int t = threadIdx.x;

  for (int e = t; e < FRT * 32; e += 256) {
    int r = e / 32, c4 = e % 32;
    float4 v = *reinterpret_cast<const float4*>(&x4[(size_t)(r0 + r) * 128 + c4 * 4]);
    unsigned short h0 = bf16hi(v.x), h1_ = bf16hi(v.y), h2 = bf16hi(v.z), h3 = bf16hi(v.w);
    xh[r][c4 * 4 + 0] = h0; xh[r][c4 * 4 + 1] = h1_;
    xh[r][c4 * 4 + 2] = h2; xh[r][c4 * 4 + 3] = h3;
    xl[r][c4 * 4 + 0] = bf16hi(v.x - bf16tof(h0));
    xl[r][c4 * 4 + 1] = bf16hi(v.y - bf16tof(h1_));
    xl[r][c4 * 4 + 2] = bf16hi(v.z - bf16tof(h2));
    xl[r][c4 * 4 + 3] = bf16hi(v.w - bf16tof(h3));
  }
  __syncthreads();

  const int l = t & 63;
  const int wv = t >> 6;
  const int arow = l & 15;
  const int kgrp = l >> 4;

  {
    short8v ahv[4], alv[4];
    #pragma unroll
    for (int ks = 0; ks < 4; ++ks) {
      ahv[ks] = *reinterpret_cast<const short8v*>(&xh[arow][ks * 32 + kgrp * 8]);
      alv[ks] = *reinterpret_cast<const short8v*>(&xl[arow][ks * 32 + kgrp * 8]);
    }
    #pragma unroll
    for (int tg = 0; tg < 16; ++tg) {
      const int tgg = wv * 16 + tg;
      f32x4v a1 = {0.f, 0.f, 0.f, 0.f};
      #pragma unroll
      for (int ks = 0; ks < 4; ++ks) {
        const unsigned short* bp = wpf1 + ((size_t)(tgg * 4 + ks) * 64 + l) * 16;
        short8v bh = *reinterpret_cast<const short8v*>(bp);
        short8v bl = *reinterpret_cast<const short8v*>(bp + 8);
        a1 = __builtin_amdgcn_mfma_f32_16x16x32_bf16(ahv[ks], bh, a1, 0, 0, 0);
        a1 = __builtin_amdgcn_mfma_f32_16x16x32_bf16(ahv[ks], bl, a1, 0, 0, 0);
        a1 = __builtin_amdgcn_mfma_f32_16x16x32_bf16(alv[ks], bh, a1, 0, 0, 0);
      }
      const int col = tgg * 16 + arow;
      const float bb = b1[col];
      #pragma unroll
      for (int i = 0; i < 4; ++i) {
        float v = fmaxf(a1[i] + bb, 0.f);
        unsigned short h = bf16hi(v);
        h1h[kgrp * 4 + i][col] = h;
        h1l[kgrp * 4 + i][col] = bf16hi(v - bf16tof(h));
      }
    }
  }
  __syncthreads();

  #pragma unroll
  for (int tc = 0; tc < 4; ++tc) {
    f32x4v accm[4];
    f32x4v zz = {0.f, 0.f, 0.f, 0.f};
    #pragma unroll
    for (int i = 0; i < 4; ++i) accm[i] = zz;

    const int tgb = wv * 16 + tc * 4;
    short8v bhC[4], blC[4], bhN[4], blN[4];
    #pragma unroll
    for (int tt = 0; tt < 4; ++tt) {
      const unsigned short* bp = wpack + ((size_t)((tgb + tt) * 32 + 0) * 64 + l) * 16;
      bhC[tt] = *reinterpret_cast<const short8v*>(bp);
      blC[tt] = *reinterpret_cast<const short8v*>(bp + 8);
    }
    for (int ks = 0; ks < 32; ++ks) {
      if (ks < 31) {
        #pragma unroll
        for (int tt = 0; tt < 4; ++tt) {
          const unsigned short* bp =
              wpack + ((size_t)((tgb + tt) * 32 + ks + 1) * 64 + l) * 16;
          bhN[tt] = *reinterpret_cast<const short8v*>(bp);
          blN[tt] = *reinterpret_cast<const short8v*>(bp + 8);
        }
      }
      const int kb = ks * 32 + kgrp * 8;
      short8v ah = *reinterpret_cast<const short8v*>(&h1h[arow][kb]);
      short8v al = *reinterpret_cast<const short8v*>(&h1l[arow][kb]);
      #pragma unroll
      for (int tt = 0; tt < 4; ++tt) {
        accm[tt] = __builtin_amdgcn_mfma_f32_16x16x32_bf16(ah, bhC[tt], accm[tt], 0, 0, 0);
        accm[tt] = __builtin_amdgcn_mfma_f32_16x16x32_bf16(ah, blC[tt], accm[tt], 0, 0, 0);
        accm[tt] = __builtin_amdgcn_mfma_f32_16x16x32_bf16(al, bhC[tt], accm[tt], 0, 0, 0);
      }
      #pragma unroll
      for (int tt = 0; tt < 4; ++tt) { bhC[tt] = bhN[tt]; blC[tt] = blN[tt]; }
    }
    #pragma unroll
    for (int tt = 0; tt < 4; ++tt) {
      float m = fmaxf(fmaxf(accm[tt][0], accm[tt][1]),
                      fmaxf(accm[tt][2], accm[tt][3]));
      m = fmaxf(m, __shfl_xor(m, 16));
      m = fmaxf(m, __shfl_xor(m, 32));
      if (kgrp == 0) {
        int n = (wv * 16 + tc * 4 + tt) * 16 + arow;
        part[(size_t)tile * 1024 + n] = m + b2[n];
      }
    }
  }
}

// --------------------------- reduce partials -> g ---------------------------
__global__ void reduce_g_kernel(const float* __restrict__ part, float* __restrict__ g) {
  int e = blockIdx.x * 256 + threadIdx.x;
  if (e >= kB * 1024) return;
  int b = e / 1024, c = e % 1024;
  const int tilesPerBatch = kN / FRT;  // 256
  const float* p = part + (size_t)b * tilesPerBatch * 1024 + c;
  float m = -INFINITY;
  for (int t = 0; t < tilesPerBatch; ++t) m = fmaxf(m, p[(size_t)t * 1024]);
  g[e] = m;
}

// --------------- per-batch head-0 g-contribution: gvec = g@W[326:]+b -------
__global__ void ghead_kernel(const float* __restrict__ g,
                             const float* __restrict__ h0W,
                             const float* __restrict__ h0b,
                             float* __restrict__ gvec) {
  const int b = blockIdx.x;
  const int n = threadIdx.x;
  float acc = h0b[n];
  const float* gb = g + (size_t)b * 1024;
  for (int k = 0; k < 1024; ++k)
    acc = fmaf(gb[k], h0W[(size_t)(326 + k) * 256 + n], acc);
  gvec[b * 256 + n] = acc;
}

// ---------- head MFMA GEMM: out = act(A@B + bias), A fp32 chunk-local ------
template <int KD, int NN>
__global__ __launch_bounds__(256) void head_mfma_kernel(
    const float* __restrict__ A, const unsigned short* __restrict__ bpk,
    const float* __restrict__ bias, float* __restrict__ out, int relu) {
  constexpr int NKS = KD / 32;
  __shared__ unsigned short ah[32][KD + 8];
  __shared__ unsigned short al[32][KD + 8];
  const int t = threadIdx.x;
  const int m0 = blockIdx.y * 32;
  const int n0 = blockIdx.x * 128;

  for (int e = t; e < 32 * (KD / 4); e += 256) {
    int r = e / (KD / 4), c4 = e % (KD / 4);
    float4 v = *reinterpret_cast<const float4*>(&A[(size_t)(m0 + r) * KD + c4 * 4]);
    unsigned short h0 = bf16hi(v.x), h1 = bf16hi(v.y), h2 = bf16hi(v.z), h3 = bf16hi(v.w);
    ah[r][c4 * 4 + 0] = h0; ah[r][c4 * 4 + 1] = h1;
    ah[r][c4 * 4 + 2] = h2; ah[r][c4 * 4 + 3] = h3;
    al[r][c4 * 4 + 0] = bf16hi(v.x - bf16tof(h0));
    al[r][c4 * 4 + 1] = bf16hi(v.y - bf16tof(h1));
    al[r][c4 * 4 + 2] = bf16hi(v.z - bf16tof(h2));
    al[r][c4 * 4 + 3] = bf16hi(v.w - bf16tof(h3));
  }
  __syncthreads();

  const int l = t & 63;
  const int wv = t >> 6;
  const int rf = wv >> 1;
  const int ch = wv & 1;
  const int arow = rf * 16 + (l & 15);
  const int kgrp = l >> 4;

  f32x4v acc[4];
  f32x4v zz = {0.f, 0.f, 0.f, 0.f};
  #pragma unroll
  for (int i = 0; i < 4; ++i) acc[i] = zz;

  for (int ks = 0; ks < NKS; ++ks) {
    const int kb = ks * 32 + kgrp * 8;
    short8v a_h = *reinterpret_cast<const short8v*>(&ah[arow][kb]);
    short8v a_l = *reinterpret_cast<const short8v*>(&al[arow][kb]);
    #pragma unroll
    for (int tg = 0; tg < 4; ++tg) {
      const int tgg = n0 / 16 + ch * 4 + tg;
      const unsigned short* bp = bpk + ((size_t)(tgg * NKS + ks) * 64 + l) * 16;
      short8v bh = *reinterpret_cast<const short8v*>(bp);
      short8v bl = *reinterpret_cast<const short8v*>(bp + 8);
      acc[tg] = __builtin_amdgcn_mfma_f32_16x16x32_bf16(a_h, bh, acc[tg], 0, 0, 0);
      acc[tg] = __builtin_amdgcn_mfma_f32_16x16x32_bf16(a_h, bl, acc[tg], 0, 0, 0);
      acc[tg] = __builtin_amdgcn_mfma_f32_16x16x32_bf16(a_l, bh, acc[tg], 0, 0, 0);
    }
  }

  #pragma unroll
  for (int tg = 0; tg < 4; ++tg) {
    int col = n0 + (ch * 4 + tg) * 16 + (l & 15);
    float bb = bias[col];
    #pragma unroll
    for (int i = 0; i < 4; ++i) {
      int row = m0 + rf * 16 + kgrp * 4 + i;
      float v = acc[tg][i] + bb;
      if (relu) v = fmaxf(v, 0.f);
      out[(size_t)row * NN + col] = v;
    }
  }
}

// ------------------------------- GEMM --------------------------------------
struct FeatSrc {
  const float* x0; const float* x1; const float* x2;
  const float* x3; const float* x4; const float* g;
};

template <int ASRC>
__device__ __forceinline__ float a_fetch(const float* __restrict__ A,
                                         const FeatSrc& fs, int row, int k, int Kd) {
  if constexpr (ASRC == 0) {
    return A[(size_t)row * Kd + k];
  } else {
    if (k < 6)        return fs.x0[(size_t)row * 8 + k];
    else if (k < 70)  return fs.x1[(size_t)row * 64 + (k - 6)];
    else if (k < 134) return fs.x2[(size_t)row * 64 + (k - 70)];
    else if (k < 198) return fs.x3[(size_t)row * 64 + (k - 134)];
    else              return fs.x4[(size_t)row * 128 + (k - 198)];
  }
}

// ---------- head-0 MFMA: gather-A (K=326 padded to 352), per-batch bias ----
__global__ __launch_bounds__(256) void head0_mfma_kernel(
    FeatSrc fs, const unsigned short* __restrict__ bpk,
    const float* __restrict__ gvec, float* __restrict__ out, int row0) {
  constexpr int KD = 352, NKS = 11, NN = 256;
  __shared__ unsigned short ah[32][KD + 8];
  __shared__ unsigned short al[32][KD + 8];
  const int t = threadIdx.x;
  const int m0 = blockIdx.y * 32;
  const int n0 = blockIdx.x * 128;

  for (int e = t; e < 32 * (KD / 4); e += 256) {
    int r = e / (KD / 4), c4 = e % (KD / 4);
    const int grow = row0 + m0 + r;
    #pragma unroll
    for (int j = 0; j < 4; ++j) {
      int k = c4 * 4 + j;
      float v = (k < 326) ? a_fetch<1>(nullptr, fs, grow, k, 0) : 0.f;
      unsigned short h = bf16hi(v);
      ah[r][k] = h;
      al[r][k] = bf16hi(v - bf16tof(h));
    }
  }
  __syncthreads();

  const int l = t & 63;
  const int wv = t >> 6;
  const int rf = wv >> 1;
  const int ch = wv & 1;
  const int arow = rf * 16 + (l & 15);
  const int kgrp = l >> 4;

  f32x4v acc[4];
  f32x4v zz = {0.f, 0.f, 0.f, 0.f};
  #pragma unroll
  for (int i = 0; i < 4; ++i) acc[i] = zz;

  for (int ks = 0; ks < NKS; ++ks) {
    const int kb = ks * 32 + kgrp * 8;
    short8v a_h = *reinterpret_cast<const short8v*>(&ah[arow][kb]);
    short8v a_l = *reinterpret_cast<const short8v*>(&al[arow][kb]);
    #pragma unroll
    for (int tg = 0; tg < 4; ++tg) {
      const int tgg = n0 / 16 + ch * 4 + tg;
      const unsigned short* bp = bpk + ((size_t)(tgg * NKS + ks) * 64 + l) * 16;
      short8v bh = *reinterpret_cast<const short8v*>(bp);
      short8v bl = *reinterpret_cast<const short8v*>(bp + 8);
      acc[tg] = __builtin_amdgcn_mfma_f32_16x16x32_bf16(a_h, bh, acc[tg], 0, 0, 0);
      acc[tg] = __builtin_amdgcn_mfma_f32_16x16x32_bf16(a_h, bl, acc[tg], 0, 0, 0);
      acc[tg] = __builtin_amdgcn_mfma_f32_16x16x32_bf16(a_l, bh, acc[tg], 0, 0, 0);
    }
  }

  const int bidx = (row0 + m0) >> 12;  // 32-row tile never crosses batch
  #pragma unroll
  for (int tg = 0; tg < 4; ++tg) {
    int col = n0 + (ch * 4 + tg) * 16 + (l & 15);
    float bb = gvec[(size_t)bidx * 256 + col];
    #pragma unroll
    for (int i = 0; i < 4; ++i) {
      int row = m0 + rf * 16 + kgrp * 4 + i;
      float v = fmaxf(acc[tg][i] + bb, 0.f);
      out[(size_t)row * NN + col] = v;
    }
  }
}

#define GBM 64
#define GBN 64
#define GBK 16

template <int ASRC>
__global__ __launch_bounds__(256) void gemm_kernel(
    const float* __restrict__ A, FeatSrc fs,
    const float* __restrict__ Bm, const float* __restrict__ bias,
    float* __restrict__ out, int row0, int Nn, int Kd, int relu, int biasb) {
  __shared__ float As[GBK][GBM + 4];
  __shared__ float Bs[GBK][GBN];

  const int tid = threadIdx.x;
  const int tx = tid % 16, ty = tid / 16;
  const int m0 = blockIdx.y * GBM;
  const int n0 = blockIdx.x * GBN;

  float acc[4][4] = {};

  for (int k0 = 0; k0 < Kd; k0 += GBK) {
    #pragma unroll
    for (int r = 0; r < 4; ++r) {
      int ee = tid + r * 256;
      int ar = ee / GBK, ak = ee % GBK;
      int kk = k0 + ak;
      float v = 0.f;
      if (kk < Kd) {
        int arow = (ASRC == 1) ? (row0 + m0 + ar) : (m0 + ar);
        v = a_fetch<ASRC>(A, fs, arow, kk, Kd);
      }
      As[ak][ar] = v;
    }
    #pragma unroll
    for (int r = 0; r < 4; ++r) {
      int ee = tid + r * 256;
      int bk = ee / GBN, bn = ee % GBN;
      int kk = k0 + bk;
      float v = 0.f;
      if (kk < Kd && (n0 + bn) < Nn) v = Bm[(size_t)kk * Nn + n0 + bn];
      Bs[bk][bn] = v;
    }
    __syncthreads();
    #pragma unroll
    for (int kk = 0; kk < GBK; ++kk) {
      float4 a4 = *reinterpret_cast<const float4*>(&As[kk][ty * 4]);
      float4 b4 = *reinterpret_cast<const float4*>(&Bs[kk][tx * 4]);
      float av[4] = {a4.x, a4.y, a4.z, a4.w};
      float bv[4] = {b4.x, b4.y, b4.z, b4.w};
      #pragma unroll
      for (int i2 = 0; i2 < 4; ++i2)
        #pragma unroll
        for (int j2 = 0; j2 < 4; ++j2)
          acc[i2][j2] = fmaf(av[i2], bv[j2], acc[i2][j2]);
    }
    __syncthreads();
  }

  #pragma unroll
  for (int j2 = 0; j2 < 4; ++j2) {
    int n = n0 + tx * 4 + j2;
    if (n >= Nn) continue;
    #pragma unroll
    for (int i2 = 0; i2 < 4; ++i2) {
      float bb;
      if (biasb) {
        int grow = row0 + m0 + ty * 4 + i2;
        bb = bias[(size_t)(grow >> 12) * 256 + n];
      } else {
        bb = bias ? bias[n] : 0.f;
      }
      float v = acc[i2][j2] + bb;
      if (relu) v = fmaxf(v, 0.f);
      out[(size_t)(m0 + ty * 4 + i2) * Nn + n] = v;
    }
  }
}

// --------- fused h3 (128->13) + log_softmax: one wave per row --------------
__global__ __launch_bounds__(256) void fused_logits_kernel(
    const float* __restrict__ h128, const float* __restrict__ W,
    const float* __restrict__ b, float* __restrict__ out, int row0) {
  __shared__ float sm[4][128];
  const int t = threadIdx.x;
  const int w = t >> 6;
  const int l = t & 63;
  const int row = blockIdx.x * 4 + w;

  sm[w][l] = h128[(size_t)row * 128 + l];
  sm[w][64 + l] = h128[(size_t)row * 128 + 64 + l];
  __syncthreads();

  float v = 0.f;
  if (l < 13) {
    for (int k = 0; k < 128; ++k) v = fmaf(sm[w][k], W[(size_t)k * 13 + l], v);
    v += b[l];
  }
  float mv = (l < 13) ? v : -INFINITY;
  #pragma unroll
  for (int off = 8; off > 0; off >>= 1) mv = fmaxf(mv, __shfl_xor(mv, off));
  float ev = (l < 13) ? expf(v - mv) : 0.f;
  float sv = ev;
  #pragma unroll
  for (int off = 8; off > 0; off >>= 1) sv += __shfl_xor(sv, off);
  if (l < 13) {
    out[(size_t)(row0 + row) * 13 + l] = v - mv - logf(sv);
  }
}

// ------------------------------- launch ------------------------------------
static void run_knn(const float* X, const float* nrm, float* Dbuf, int* nidx,
                    int CS, int dq, hipStream_t stream) {
  for (int b = 0; b < kB; ++b) {
    for (int h = 0; h < kN / dq; ++h) {
      dim3 g(kN / 64, dq / 64);
      if (CS == 8)
        dist_gemm_kernel<8><<<g, 256, 0, stream>>>(
            X + (size_t)b * kN * 8, nrm + (size_t)b * kN, Dbuf, h * dq);
      else
        dist_gemm_kernel<64><<<g, 256, 0, stream>>>(
            X + (size_t)b * kN * 64, nrm + (size_t)b * kN, Dbuf, h * dq);
      knn_select_kernel<<<dq / 4, 256, 0, stream>>>(Dbuf, nidx,
                                                    b * kN + h * dq);
    }
  }
}

extern "C" void kernel_launch(void* const* d_in, const int* in_sizes, int n_in,
                              void* d_out, int out_size, void* d_ws, size_t ws_size,
                              hipStream_t stream) {
  const float* x    = (const float*)d_in[0];
  const float* pos  = (const float*)d_in[1];
  const float* e1W1 = (const float*)d_in[2];
  const float* e1b1 = (const float*)d_in[3];
  const float* e1W2 = (const float*)d_in[4];
  const float* e1b2 = (const float*)d_in[5];
  const float* e2W1 = (const float*)d_in[6];
  const float* e2b1 = (const float*)d_in[7];
  const float* e2W2 = (const float*)d_in[8];
  const float* e2b2 = (const float*)d_in[9];
  const float* e3W1 = (const float*)d_in[10];
  const float* e3b1 = (const float*)d_in[11];
  const float* e3W2 = (const float*)d_in[12];
  const float* e3b2 = (const float*)d_in[13];
  const float* e4W1 = (const float*)d_in[14];
  const float* e4b1 = (const float*)d_in[15];
  const float* e4W2 = (const float*)d_in[16];
  const float* e4b2 = (const float*)d_in[17];
  const float* feW1 = (const float*)d_in[18];
  const float* feb1 = (const float*)d_in[19];
  const float* feW2 = (const float*)d_in[20];
  const float* feb2 = (const float*)d_in[21];
  const float* h0W  = (const float*)d_in[22];
  const float* h0b  = (const float*)d_in[23];
  const float* h1W  = (const float*)d_in[24];
  const float* h1b  = (const float*)d_in[25];
  const float* h2W  = (const float*)d_in[26];
  const float* h2b  = (const float*)d_in[27];
  const float* h3W  = (const float*)d_in[28];
  const float* h3b  = (const float*)d_in[29];

  float* W = (float*)d_ws;
  size_t off = 0;
  float* x0p  = W + off; off += (size_t)kBN * 8;
  float* x1   = W + off; off += (size_t)kBN * 64;
  float* x2   = W + off; off += (size_t)kBN * 64;
  float* x3   = W + off; off += (size_t)kBN * 64;
  float* x4   = W + off; off += (size_t)kBN * 128;
  float* gmax = W + off; off += (size_t)kB * 1024;
  float* gvec = W + off; off += (size_t)kB * 256;
  float* nrm  = W + off; off += (size_t)kBN;
  int*   nidx = (int*)(W + off); off += (size_t)kBN * kK;
  float* wu   = W + off; off += (size_t)64 * 256;
  float* b1e  = W + off; off += 256;
  unsigned short* wpack = (unsigned short*)(W + off); off += (size_t)1048576; // 4MB
  unsigned short* wpk4  = (unsigned short*)(W + off); off += (size_t)16384;   // 64KB
  unsigned short* wph1  = (unsigned short*)(W + off); off += (size_t)65536;   // 256KB
  unsigned short* wph2  = (unsigned short*)(W + off); off += (size_t)32768;   // 128KB
  unsigned short* wpf1  = (unsigned short*)(W + off); off += (size_t)131072;  // 512KB
  unsigned short* wph0  = (unsigned short*)(W + off); off += (size_t)90112;   // 352KB
  // transient union: D chunk / uv (33.5MB) / fe part / head bufs
  float* trans = W + off;
  float* Dbuf = trans;
  float* uv   = trans;
  float* part = trans;

  // runtime-gated kNN D-chunk: 4096 rows (64MB) if workspace allows
  const size_t need4096 = (off + (size_t)4096 * kN) * 4;
  const int dq = (ws_size >= need4096) ? 4096 : 2048;

  // runtime-gated head chunk: single 32768-row chunk (83.9MB) if it fits
  const size_t need_single = (off + (size_t)32768 * 640) * 4;
  const int ch_rows = (ws_size >= need_single) ? 32768 : 8192;
  float* ping = trans;
  float* pong = ping + (size_t)ch_rows * 256;
  float* h128 = pong + (size_t)ch_rows * 256;

  FeatSrc fs{x0p, x1, x2, x3, x4, gmax};

  concat_x0_kernel<<<(kBN * 8 + 255) / 256, 256, 0, stream>>>(x, pos, x0p);

  // ---- edge conv 1: C=6 (CS=8), H1=64, H2=64 ----
  norms_kernel<6, 8><<<(kBN + 255) / 256, 256, 0, stream>>>(x0p, nrm);
  run_knn(x0p, nrm, Dbuf, nidx, 8, dq, stream);
  prep_uv_kernel<<<(8 * 128 + 255) / 256, 256, 0, stream>>>(e1W1, e1b1, wu, b1e, 6, 64, 8);
  gemm_kernel<0><<<dim3(128 / GBN, kBN / GBM), 256, 0, stream>>>(
      x0p, fs, wu, b1e, uv, 0, 128, 8, 0, 0);
  gather_gemm2_max_kernel<64><<<dim3(1, kBN / 2), 256, 0, stream>>>(
      uv, nidx, e1W2, e1b2, x1, 64);

  // ---- edge conv 2: C=64, H1=64, H2=64 ----
  norms_kernel<64, 64><<<(kBN + 255) / 256, 256, 0, stream>>>(x1, nrm);
  run_knn(x1, nrm, Dbuf, nidx, 64, dq, stream);
  prep_uv_kernel<<<(64 * 128 + 255) / 256, 256, 0, stream>>>(e2W1, e2b1, wu, b1e, 64, 64, 64);
  gemm_kernel<0><<<dim3(128 / GBN, kBN / GBM), 256, 0, stream>>>(
      x1, fs, wu, b1e, uv, 0, 128, 64, 0, 0);
  gather_gemm2_max_kernel<64><<<dim3(1, kBN / 2), 256, 0, stream>>>(
      uv, nidx, e2W2, e2b2, x2, 64);

  // ---- edge conv 3 ----
  norms_kernel<64, 64><<<(kBN + 255) / 256, 256, 0, stream>>>(x2, nrm);
  run_knn(x2, nrm, Dbuf, nidx, 64, dq, stream);
  prep_uv_kernel<<<(64 * 128 + 255) / 256, 256, 0, stream>>>(e3W1, e3b1, wu, b1e, 64, 64, 64);
  gemm_kernel<0><<<dim3(128 / GBN, kBN / GBM), 256, 0, stream>>>(
      x2, fs, wu, b1e, uv, 0, 128, 64, 0, 0);
  gather_gemm2_max_kernel<64><<<dim3(1, kBN / 2), 256, 0, stream>>>(
      uv, nidx, e3W2, e3b2, x3, 64);

  // ---- edge conv 4: C=64, H1=128, H2=128 (MFMA gather) ----
  norms_kernel<64, 64><<<(kBN + 255) / 256, 256, 0, stream>>>(x3, nrm);
  run_knn(x3, nrm, Dbuf, nidx, 64, dq, stream);
  prep_uv_kernel<<<(64 * 256 + 255) / 256, 256, 0, stream>>>(e4W1, e4b1, wu, b1e, 64, 128, 64);
  gemm_kernel<0><<<dim3(256 / GBN, kBN / GBM), 256, 0, stream>>>(
      x3, fs, wu, b1e, uv, 0, 256, 64, 0, 0);
  pack_w2gen_kernel<<<64, 256, 0, stream>>>(e4W2, wpk4, 128, 128);
  gather_mfma_max_kernel<<<kBN / 4, 256, 0, stream>>>(uv, nidx, wpk4, e4b2, x4);

  // ---- fe fused (both phases MFMA) + global max + ghead ----
  pack_w2_kernel<<<4096, 256, 0, stream>>>(feW2, wpack);
  pack_w2gen_kernel<<<512, 256, 0, stream>>>(feW1, wpf1, 128, 1024);
  fe_fused_kernel<<<kBN / FRT, 256, 0, stream>>>(x4, wpf1, feb1, wpack, feb2, part);
  reduce_g_kernel<<<(kB * 1024 + 255) / 256, 256, 0, stream>>>(part, gmax);
  ghead_kernel<<<kB, 256, 0, stream>>>(gmax, h0W, h0b, gvec);

  // ---- pack head weights for MFMA ----
  pack_h0_kernel<<<(16 * 11 * 512 + 255) / 256, 256, 0, stream>>>(h0W, wph0);
  pack_w2gen_kernel<<<(16 * 8 * 512 + 255) / 256, 256, 0, stream>>>(h1W, wph1, 256, 256);
  pack_w2gen_kernel<<<(8 * 8 * 512 + 255) / 256, 256, 0, stream>>>(h2W, wph2, 256, 128);

  // ---- head, chunked over rows (single chunk when ws allows) ----
  for (int row0 = 0; row0 < kBN; row0 += ch_rows) {
    head0_mfma_kernel<<<dim3(2, ch_rows / 32), 256, 0, stream>>>(
        fs, wph0, gvec, ping, row0);
    head_mfma_kernel<256, 256><<<dim3(2, ch_rows / 32), 256, 0, stream>>>(
        ping, wph1, h1b, pong, 1);
    head_mfma_kernel<256, 128><<<dim3(1, ch_rows / 32), 256, 0, stream>>>(
        pong, wph2, h2b, h128, 1);
    fused_logits_kernel<<<ch_rows / 4, 256, 0, stream>>>(
        h128, h3W, h3b, (float*)d_out, row0);
  }
}